// Round 9
// baseline (217.663 us; speedup 1.0000x reference)
//
#include <hip/hip_runtime.h>

typedef __attribute__((ext_vector_type(8))) short bf16x8;
typedef __attribute__((ext_vector_type(4))) float f32x4;
typedef __attribute__((ext_vector_type(16))) float f32x16;

union BFU { uint4 q; bf16x8 v; };

__device__ __forceinline__ unsigned short f2bf(float f) {
  unsigned u = __float_as_uint(f);
  u += 0x7fff + ((u >> 16) & 1);
  return (unsigned short)(u >> 16);
}
__device__ __forceinline__ unsigned pk2(float a, float b) {
  return (unsigned)f2bf(a) | ((unsigned)f2bf(b) << 16);
}
__device__ __forceinline__ unsigned cvtpk(float lo, float hi) {
  unsigned d;
  asm("v_cvt_pk_bf16_f32 %0, %1, %2" : "=v"(d) : "v"(lo), "v"(hi));
  return d;
}
__device__ __forceinline__ float xhalf_sum(float x) {
  return x + __shfl_xor(x, 32);
}

#define S_LEN 2048
#define DH 64
#define LOG2E 1.4426950408889634f
#define PSTRIDE 9216   // bytes per partial: 64 lanes * 144B

// ---- pre-pass: fragment-major bf16 tiles (proven R7/R8) --------------------
__global__ __launch_bounds__(256) void prepack(const float* __restrict__ K,
                                               const float* __restrict__ V,
                                               unsigned char* __restrict__ wsK,
                                               unsigned char* __restrict__ wsVt) {
  const int t = threadIdx.x;
  const int bid = blockIdx.x;              // bh*32 + kt
  const size_t gbase = (size_t)bid * 4096;
  const int row = t & 63;
  const int j = t >> 6;                    // 0..3
  unsigned char* obK = wsK + (size_t)bid * 8192;
  unsigned char* obV = wsVt + (size_t)bid * 8192;
#pragma unroll
  for (int gg = 0; gg < 2; ++gg) {
    const int g = j + gg * 4;              // 0..7
    {
      const float* kg = K + gbase + (size_t)row * DH + g * 8;
      float4 x = *(const float4*)kg;
      float4 y = *(const float4*)(kg + 4);
      uint4 h;
      h.x = pk2(x.x, x.y); h.y = pk2(x.z, x.w);
      h.z = pk2(y.x, y.y); h.w = pk2(y.z, y.w);
      *(uint4*)(obK + g * 1024 + row * 16) = h;
    }
    {
      const float* vg = V + gbase + row;
      float v0 = vg[(size_t)(g * 8 + 0) * DH], v1 = vg[(size_t)(g * 8 + 1) * DH];
      float v2 = vg[(size_t)(g * 8 + 2) * DH], v3 = vg[(size_t)(g * 8 + 3) * DH];
      float v4 = vg[(size_t)(g * 8 + 4) * DH], v5 = vg[(size_t)(g * 8 + 5) * DH];
      float v6 = vg[(size_t)(g * 8 + 6) * DH], v7 = vg[(size_t)(g * 8 + 7) * DH];
      uint4 h;
      h.x = pk2(v0, v1); h.y = pk2(v2, v3);
      h.z = pk2(v4, v5); h.w = pk2(v6, v7);
      *(uint4*)(obV + g * 1024 + row * 16) = h;
    }
  }
}

// ---- split-K main: 1-wave blocks, fixed-m ghost softmax, 4 waves/SIMD ------
// grid = 32 bh * 95:  u<62: heavy (qt=63-(u>>1), part=u&1, kv-split);
//                     u>=62: light (qt=32-(u-62)), direct O write.
__global__ __launch_bounds__(64, 4) void fattn9(const float* __restrict__ Q,
                                                const unsigned char* __restrict__ wsK,
                                                const unsigned char* __restrict__ wsVt,
                                                unsigned char* __restrict__ pws,
                                                float* __restrict__ O) {
  const int lane = threadIdx.x;
  const int c = lane & 31;
  const int hi = lane >> 5;

  const int bid = blockIdx.x;
  const int bh = bid & 31;
  const int u = bid >> 5;                  // 0..94, LPT (longest first)
  const bool heavy = (u < 62);
  const int qt = heavy ? (63 - (u >> 1)) : (32 - (u - 62));
  const int part = heavy ? (u & 1) : 0;

  // ---- Q fragments (B-operand: col=q=c, k=d), scale (1/8)*log2e ----
  const float* qrow = Q + ((size_t)(bh * S_LEN) + qt * 32 + c) * DH;
  BFU qf[4];
#pragma unroll
  for (int i = 0; i < 4; ++i) {
    const int d0 = i * 16 + hi * 8;
    float4 x = *(const float4*)(qrow + d0);
    float4 y = *(const float4*)(qrow + d0 + 4);
    const float sc = 0.125f * LOG2E;
    qf[i].q.x = pk2(x.x * sc, x.y * sc);
    qf[i].q.y = pk2(x.z * sc, x.w * sc);
    qf[i].q.z = pk2(y.x * sc, y.y * sc);
    qf[i].q.w = pk2(y.z * sc, y.w * sc);
  }

  f32x16 acc0, acc1;
#pragma unroll
  for (int r = 0; r < 16; ++r) { acc0[r] = 0.f; acc1[r] = 0.f; }
  float sacc[16];
#pragma unroll
  for (int r = 0; r < 16; ++r) sacc[r] = 0.f;

  const unsigned char* tbK = wsK + (size_t)bh * 32 * 8192;
  const unsigned char* tbV = wsVt + (size_t)bh * 32 * 8192;
  const int fo = hi * 1024 + c * 16;

  const int NT = (qt + 1) >> 1;            // full 64-kv tiles
  const int last = qt >> 1;                // max tile index incl. tail
  const int NTH = NT - (NT >> 1);          // ceil(NT/2): part0 size
  const int t0 = (heavy && part == 1) ? NTH : 0;
  const int t1 = (heavy && part == 0) ? NTH : NT;
  const bool dotail = (!(qt & 1)) && (!heavy || part == 1);

  BFU kf0[4], kf1[4], vf0[4], vf1[4];
#define LOADK(tile_)                                                       \
  {                                                                        \
    const unsigned char* kb_ = tbK + (size_t)(tile_) * 8192;               \
    _Pragma("unroll")                                                      \
    for (int i = 0; i < 4; ++i) {                                          \
      kf0[i].q = *(const uint4*)(kb_ + i * 2048 + fo);                     \
      kf1[i].q = *(const uint4*)(kb_ + i * 2048 + fo + 512);               \
    }                                                                      \
  }
#define LOADV(tile_)                                                       \
  {                                                                        \
    const unsigned char* vb_ = tbV + (size_t)(tile_) * 8192;               \
    _Pragma("unroll")                                                      \
    for (int i = 0; i < 4; ++i) {                                          \
      vf0[i].q = *(const uint4*)(vb_ + i * 2048 + fo);                     \
      vf1[i].q = *(const uint4*)(vb_ + i * 2048 + fo + 512);               \
    }                                                                      \
  }
#define MAKEPF(dst, x0, x1, x2, x3, y0, y1, y2, y3)                  \
    {                                                                \
      unsigned a01 = cvtpk(x0, x1), a23 = cvtpk(x2, x3);             \
      unsigned b01 = cvtpk(y0, y1), b23 = cvtpk(y2, y3);             \
      asm("v_permlane32_swap_b32 %0, %1" : "+v"(a01), "+v"(b01));    \
      asm("v_permlane32_swap_b32 %0, %1" : "+v"(a23), "+v"(b23));    \
      (dst).q.x = a01; (dst).q.y = a23; (dst).q.z = b01; (dst).q.w = b23; \
    }

  LOADK(t0)
  LOADV(t0)

  for (int kt = t0; kt < t1; ++kt) {
    // ---- QK^T (swapped): S^T[kv][q] = mfma(A=K, B=Q) ----
    f32x16 st0, st1;
#pragma unroll
    for (int r = 0; r < 16; ++r) { st0[r] = 0.f; st1[r] = 0.f; }
    __builtin_amdgcn_s_setprio(1);
#pragma unroll
    for (int i = 0; i < 4; ++i) {
      st0 = __builtin_amdgcn_mfma_f32_32x32x16_bf16(kf0[i].v, qf[i].v, st0, 0, 0, 0);
      st1 = __builtin_amdgcn_mfma_f32_32x32x16_bf16(kf1[i].v, qf[i].v, st1, 0, 0, 0);
    }
    __builtin_amdgcn_s_setprio(0);

    if (kt + 1 <= last) LOADK(kt + 1)

    // odd qt: last full tile straddles the diagonal (always in part1/light)
    if ((qt & 1) && kt == NT - 1) {
#pragma unroll
      for (int r = 0; r < 16; ++r) {
        const int kvloc = (r & 3) + 8 * (r >> 2) + 4 * hi;
        if (kvloc > c) st1[r] = -1e9f;
      }
    }

    // ---- fixed-m ghost softmax: P = exp2(s); denominator deferred ----
#pragma unroll
    for (int r = 0; r < 16; ++r) { st0[r] = exp2f(st0[r]); st1[r] = exp2f(st1[r]); }
#pragma unroll
    for (int r = 0; r < 16; ++r) sacc[r] += st0[r] + st1[r];

    BFU pf[4];
    MAKEPF(pf[0], st0[0], st0[1], st0[2], st0[3], st0[4], st0[5], st0[6], st0[7])
    MAKEPF(pf[1], st0[8], st0[9], st0[10], st0[11], st0[12], st0[13], st0[14], st0[15])
    MAKEPF(pf[2], st1[0], st1[1], st1[2], st1[3], st1[4], st1[5], st1[6], st1[7])
    MAKEPF(pf[3], st1[8], st1[9], st1[10], st1[11], st1[12], st1[13], st1[14], st1[15])

    __builtin_amdgcn_s_setprio(1);
#pragma unroll
    for (int kvt = 0; kvt < 4; ++kvt) {
      acc0 = __builtin_amdgcn_mfma_f32_32x32x16_bf16(vf0[kvt].v, pf[kvt].v, acc0, 0, 0, 0);
      acc1 = __builtin_amdgcn_mfma_f32_32x32x16_bf16(vf1[kvt].v, pf[kvt].v, acc1, 0, 0, 0);
    }
    __builtin_amdgcn_s_setprio(0);

    if (kt + 1 <= last) LOADV(kt + 1)
  }

  // ---- even qt: diagonal half-tile (kv 0..31 of tile 'last'), st0 only ----
  if (dotail) {
    f32x16 st0;
#pragma unroll
    for (int r = 0; r < 16; ++r) st0[r] = 0.f;
    __builtin_amdgcn_s_setprio(1);
#pragma unroll
    for (int i = 0; i < 4; ++i)
      st0 = __builtin_amdgcn_mfma_f32_32x32x16_bf16(kf0[i].v, qf[i].v, st0, 0, 0, 0);
    __builtin_amdgcn_s_setprio(0);
#pragma unroll
    for (int r = 0; r < 16; ++r) {
      const int kvloc = (r & 3) + 8 * (r >> 2) + 4 * hi;
      st0[r] = (kvloc > c) ? 0.f : exp2f(st0[r]);
    }
#pragma unroll
    for (int r = 0; r < 16; ++r) sacc[r] += st0[r];
    BFU pf0, pf1;
    MAKEPF(pf0, st0[0], st0[1], st0[2], st0[3], st0[4], st0[5], st0[6], st0[7])
    MAKEPF(pf1, st0[8], st0[9], st0[10], st0[11], st0[12], st0[13], st0[14], st0[15])
    __builtin_amdgcn_s_setprio(1);
    acc0 = __builtin_amdgcn_mfma_f32_32x32x16_bf16(vf0[0].v, pf0.v, acc0, 0, 0, 0);
    acc0 = __builtin_amdgcn_mfma_f32_32x32x16_bf16(vf0[1].v, pf1.v, acc0, 0, 0, 0);
    acc1 = __builtin_amdgcn_mfma_f32_32x32x16_bf16(vf1[0].v, pf0.v, acc1, 0, 0, 0);
    acc1 = __builtin_amdgcn_mfma_f32_32x32x16_bf16(vf1[1].v, pf1.v, acc1, 0, 0, 0);
    __builtin_amdgcn_s_setprio(0);
  }
#undef MAKEPF
#undef LOADK
#undef LOADV

  // ---- per-lane denominator partial (tree); ghost +1 added at the end ----
#pragma unroll
  for (int off = 8; off >= 1; off >>= 1)
#pragma unroll
    for (int r = 0; r < 8; ++r)
      if (r < off) sacc[r] += sacc[r + off];

  if (!heavy) {
    const float lrun = 1.f + xhalf_sum(sacc[0]);
    const float inv = 1.f / lrun;
    float* orow = O + ((size_t)(bh * S_LEN) + qt * 32 + c) * DH;
#pragma unroll
    for (int k = 0; k < 4; ++k) {
      float4 o0, o1;
      o0.x = acc0[4 * k] * inv;     o0.y = acc0[4 * k + 1] * inv;
      o0.z = acc0[4 * k + 2] * inv; o0.w = acc0[4 * k + 3] * inv;
      o1.x = acc1[4 * k] * inv;     o1.y = acc1[4 * k + 1] * inv;
      o1.z = acc1[4 * k + 2] * inv; o1.w = acc1[4 * k + 3] * inv;
      *(float4*)(orow + 8 * k + 4 * hi) = o0;
      *(float4*)(orow + 32 + 8 * k + 4 * hi) = o1;
    }
  } else {
    // partial: pid = bh*62 + u; per lane 144B: acc0(64) acc1(64) l(4)
    unsigned char* base = pws + (size_t)(bh * 62 + u) * PSTRIDE + lane * 144;
#pragma unroll
    for (int k = 0; k < 4; ++k) {
      float4 a0, a1;
      a0.x = acc0[4 * k];     a0.y = acc0[4 * k + 1];
      a0.z = acc0[4 * k + 2]; a0.w = acc0[4 * k + 3];
      a1.x = acc1[4 * k];     a1.y = acc1[4 * k + 1];
      a1.z = acc1[4 * k + 2]; a1.w = acc1[4 * k + 3];
      *(float4*)(base + k * 16) = a0;
      *(float4*)(base + 64 + k * 16) = a1;
    }
    *(float*)(base + 128) = sacc[0];
  }
}

// ---- combine: O = (accA+accB) / (1 + lA + lB) ------------------------------
__global__ __launch_bounds__(64) void combine(const unsigned char* __restrict__ pws,
                                              float* __restrict__ O) {
  const int lane = threadIdx.x;
  const int c = lane & 31;
  const int hi = lane >> 5;
  const int bh = blockIdx.x & 31;
  const int j = blockIdx.x >> 5;       // 0..30 -> qt = 63-j
  const int qt = 63 - j;
  const unsigned char* p0 = pws + (size_t)(bh * 62 + 2 * j) * PSTRIDE + lane * 144;
  const unsigned char* p1 = p0 + PSTRIDE;

  float a0[16], a1[16];
#pragma unroll
  for (int k = 0; k < 4; ++k) {
    float4 x0 = *(const float4*)(p0 + k * 16);
    float4 y0 = *(const float4*)(p1 + k * 16);
    a0[4 * k] = x0.x + y0.x; a0[4 * k + 1] = x0.y + y0.y;
    a0[4 * k + 2] = x0.z + y0.z; a0[4 * k + 3] = x0.w + y0.w;
    float4 x1 = *(const float4*)(p0 + 64 + k * 16);
    float4 y1 = *(const float4*)(p1 + 64 + k * 16);
    a1[4 * k] = x1.x + y1.x; a1[4 * k + 1] = x1.y + y1.y;
    a1[4 * k + 2] = x1.z + y1.z; a1[4 * k + 3] = x1.w + y1.w;
  }
  const float lp = *(const float*)(p0 + 128) + *(const float*)(p1 + 128);
  const float lrun = 1.f + xhalf_sum(lp);
  const float inv = 1.f / lrun;
  float* orow = O + ((size_t)(bh * S_LEN) + qt * 32 + c) * DH;
#pragma unroll
  for (int k = 0; k < 4; ++k) {
    float4 o0, o1;
    o0.x = a0[4 * k] * inv;     o0.y = a0[4 * k + 1] * inv;
    o0.z = a0[4 * k + 2] * inv; o0.w = a0[4 * k + 3] * inv;
    o1.x = a1[4 * k] * inv;     o1.y = a1[4 * k + 1] * inv;
    o1.z = a1[4 * k + 2] * inv; o1.w = a1[4 * k + 3] * inv;
    *(float4*)(orow + 8 * k + 4 * hi) = o0;
    *(float4*)(orow + 32 + 8 * k + 4 * hi) = o1;
  }
}

// ---- mid-tier: R8 kernel (proven 49.7us) for 16MB <= ws < 35MB -------------
__global__ __launch_bounds__(64) void fattn8(const float* __restrict__ Q,
                                             const unsigned char* __restrict__ wsK,
                                             const unsigned char* __restrict__ wsVt,
                                             float* __restrict__ O) {
  const int lane = threadIdx.x;
  const int c = lane & 31;
  const int hi = lane >> 5;

  const int bid = blockIdx.x;
  const int bh = bid & 31;
  const int qt = 63 - (bid >> 5);

  const float* qrow = Q + ((size_t)(bh * S_LEN) + qt * 32 + c) * DH;
  BFU qf[4];
#pragma unroll
  for (int i = 0; i < 4; ++i) {
    const int d0 = i * 16 + hi * 8;
    float4 x = *(const float4*)(qrow + d0);
    float4 y = *(const float4*)(qrow + d0 + 4);
    const float sc = 0.125f * LOG2E;
    qf[i].q.x = pk2(x.x * sc, x.y * sc);
    qf[i].q.y = pk2(x.z * sc, x.w * sc);
    qf[i].q.z = pk2(y.x * sc, y.y * sc);
    qf[i].q.w = pk2(y.z * sc, y.w * sc);
  }

  f32x16 acc0, acc1;
#pragma unroll
  for (int r = 0; r < 16; ++r) { acc0[r] = 0.f; acc1[r] = 0.f; }
  float sacc[16];
#pragma unroll
  for (int r = 0; r < 16; ++r) sacc[r] = 0.f;

  const unsigned char* tbK = wsK + (size_t)bh * 32 * 8192;
  const unsigned char* tbV = wsVt + (size_t)bh * 32 * 8192;
  const int fo = hi * 1024 + c * 16;

  const int NT = (qt + 1) >> 1;
  const int last = qt >> 1;

  BFU kf0[4], kf1[4], vf0[4], vf1[4];
#define LOADK(tile_)                                                       \
  {                                                                        \
    const unsigned char* kb_ = tbK + (size_t)(tile_) * 8192;               \
    _Pragma("unroll")                                                      \
    for (int i = 0; i < 4; ++i) {                                          \
      kf0[i].q = *(const uint4*)(kb_ + i * 2048 + fo);                     \
      kf1[i].q = *(const uint4*)(kb_ + i * 2048 + fo + 512);               \
    }                                                                      \
  }
#define LOADV(tile_)                                                       \
  {                                                                        \
    const unsigned char* vb_ = tbV + (size_t)(tile_) * 8192;               \
    _Pragma("unroll")                                                      \
    for (int i = 0; i < 4; ++i) {                                          \
      vf0[i].q = *(const uint4*)(vb_ + i * 2048 + fo);                     \
      vf1[i].q = *(const uint4*)(vb_ + i * 2048 + fo + 512);               \
    }                                                                      \
  }
#define QK8(D0, D1)                                                        \
  {                                                                        \
    _Pragma("unroll")                                                      \
    for (int r = 0; r < 16; ++r) { (D0)[r] = 0.f; (D1)[r] = 0.f; }         \
    __builtin_amdgcn_s_setprio(1);                                         \
    _Pragma("unroll")                                                      \
    for (int i = 0; i < 4; ++i) {                                          \
      (D0) = __builtin_amdgcn_mfma_f32_32x32x16_bf16(kf0[i].v, qf[i].v, (D0), 0, 0, 0); \
      (D1) = __builtin_amdgcn_mfma_f32_32x32x16_bf16(kf1[i].v, qf[i].v, (D1), 0, 0, 0); \
    }                                                                      \
    __builtin_amdgcn_s_setprio(0);                                         \
  }
#define MAKEPF(dst, x0, x1, x2, x3, y0, y1, y2, y3)                  \
    {                                                                \
      unsigned a01 = cvtpk(x0, x1), a23 = cvtpk(x2, x3);             \
      unsigned b01 = cvtpk(y0, y1), b23 = cvtpk(y2, y3);             \
      asm("v_permlane32_swap_b32 %0, %1" : "+v"(a01), "+v"(b01));    \
      asm("v_permlane32_swap_b32 %0, %1" : "+v"(a23), "+v"(b23));    \
      (dst).q.x = a01; (dst).q.y = a23; (dst).q.z = b01; (dst).q.w = b23; \
    }
#define BODY(S0, S1, N0, N1, KT)                                           \
  {                                                                        \
    if ((KT) + 1 < NT) QK8(N0, N1)                                         \
    if ((KT) + 2 <= last) LOADK((KT) + 2)                                  \
    if ((qt & 1) && (KT) == NT - 1) {                                      \
      _Pragma("unroll")                                                    \
      for (int r = 0; r < 16; ++r) {                                       \
        const int kvloc = (r & 3) + 8 * (r >> 2) + 4 * hi;                 \
        if (kvloc > c) (S1)[r] = -1e9f;                                    \
      }                                                                    \
    }                                                                      \
    _Pragma("unroll")                                                      \
    for (int r = 0; r < 16; ++r) { (S0)[r] = exp2f((S0)[r]); (S1)[r] = exp2f((S1)[r]); } \
    _Pragma("unroll")                                                      \
    for (int r = 0; r < 16; ++r) sacc[r] += (S0)[r] + (S1)[r];             \
    BFU pf[4];                                                             \
    MAKEPF(pf[0], (S0)[0], (S0)[1], (S0)[2], (S0)[3], (S0)[4], (S0)[5], (S0)[6], (S0)[7])  \
    MAKEPF(pf[1], (S0)[8], (S0)[9], (S0)[10], (S0)[11], (S0)[12], (S0)[13], (S0)[14], (S0)[15]) \
    MAKEPF(pf[2], (S1)[0], (S1)[1], (S1)[2], (S1)[3], (S1)[4], (S1)[5], (S1)[6], (S1)[7])  \
    MAKEPF(pf[3], (S1)[8], (S1)[9], (S1)[10], (S1)[11], (S1)[12], (S1)[13], (S1)[14], (S1)[15]) \
    __builtin_amdgcn_s_setprio(1);                                         \
    _Pragma("unroll")                                                      \
    for (int kvt = 0; kvt < 4; ++kvt) {                                    \
      acc0 = __builtin_amdgcn_mfma_f32_32x32x16_bf16(vf0[kvt].v, pf[kvt].v, acc0, 0, 0, 0); \
      acc1 = __builtin_amdgcn_mfma_f32_32x32x16_bf16(vf1[kvt].v, pf[kvt].v, acc1, 0, 0, 0); \
    }                                                                      \
    __builtin_amdgcn_s_setprio(0);                                         \
    if ((KT) + 1 <= last) LOADV((KT) + 1)                                  \
  }

  LOADK(0)
  LOADV(0)

  f32x16 stA0, stA1, stB0, stB1;
  QK8(stA0, stA1)
  if (1 <= last) LOADK(1)

  int kt = 0;
  for (; kt + 1 < NT; kt += 2) {
    BODY(stA0, stA1, stB0, stB1, kt)
    BODY(stB0, stB1, stA0, stA1, kt + 1)
  }
  if (kt < NT) BODY(stA0, stA1, stB0, stB1, kt)

  if (!(qt & 1)) {
    f32x16 st0;
#pragma unroll
    for (int r = 0; r < 16; ++r) st0[r] = 0.f;
    __builtin_amdgcn_s_setprio(1);
#pragma unroll
    for (int i = 0; i < 4; ++i)
      st0 = __builtin_amdgcn_mfma_f32_32x32x16_bf16(kf0[i].v, qf[i].v, st0, 0, 0, 0);
    __builtin_amdgcn_s_setprio(0);
#pragma unroll
    for (int r = 0; r < 16; ++r) {
      const int kvloc = (r & 3) + 8 * (r >> 2) + 4 * hi;
      st0[r] = (kvloc > c) ? 0.f : exp2f(st0[r]);
    }
#pragma unroll
    for (int r = 0; r < 16; ++r) sacc[r] += st0[r];
    BFU pf0, pf1;
    MAKEPF(pf0, st0[0], st0[1], st0[2], st0[3], st0[4], st0[5], st0[6], st0[7])
    MAKEPF(pf1, st0[8], st0[9], st0[10], st0[11], st0[12], st0[13], st0[14], st0[15])
    __builtin_amdgcn_s_setprio(1);
    acc0 = __builtin_amdgcn_mfma_f32_32x32x16_bf16(vf0[0].v, pf0.v, acc0, 0, 0, 0);
    acc0 = __builtin_amdgcn_mfma_f32_32x32x16_bf16(vf0[1].v, pf1.v, acc0, 0, 0, 0);
    acc1 = __builtin_amdgcn_mfma_f32_32x32x16_bf16(vf1[0].v, pf0.v, acc1, 0, 0, 0);
    acc1 = __builtin_amdgcn_mfma_f32_32x32x16_bf16(vf1[1].v, pf1.v, acc1, 0, 0, 0);
    __builtin_amdgcn_s_setprio(0);
  }
#undef BODY
#undef MAKEPF
#undef QK8
#undef LOADK
#undef LOADV

#pragma unroll
  for (int off = 8; off >= 1; off >>= 1)
#pragma unroll
    for (int r = 0; r < 8; ++r)
      if (r < off) sacc[r] += sacc[r + off];
  const float lrun = 1.f + xhalf_sum(sacc[0]);

  const float inv = 1.f / lrun;
  float* orow = O + ((size_t)(bh * S_LEN) + qt * 32 + c) * DH;
#pragma unroll
  for (int k = 0; k < 4; ++k) {
    float4 o0, o1;
    o0.x = acc0[4 * k] * inv;     o0.y = acc0[4 * k + 1] * inv;
    o0.z = acc0[4 * k + 2] * inv; o0.w = acc0[4 * k + 3] * inv;
    o1.x = acc1[4 * k] * inv;     o1.y = acc1[4 * k + 1] * inv;
    o1.z = acc1[4 * k + 2] * inv; o1.w = acc1[4 * k + 3] * inv;
    *(float4*)(orow + 8 * k + 4 * hi) = o0;
    *(float4*)(orow + 32 + 8 * k + 4 * hi) = o1;
  }
}

// ---------------- fallback (R2 staging kernel) if ws too small ----------------
__global__ __launch_bounds__(256) void fattn_fb(const float* __restrict__ Q,
                                                const float* __restrict__ K,
                                                const float* __restrict__ V,
                                                float* __restrict__ O) {
  __shared__ __align__(16) unsigned char lds[24 * 1024];
  unsigned char* kb = lds;
  unsigned char* vb = lds + 8192;
  const int t = threadIdx.x;
  const int lane = t & 63;
  const int w = t >> 6;
  const int g = lane >> 4;
  const int n = lane & 15;
  unsigned char* pb = lds + 16384 + w * 2048;

  const int bid = blockIdx.x;
  const int bh = bid & 31;
  const int qt = bid >> 5;
  const int q0 = qt * 64;

  const float* qg = Q + ((size_t)(bh * S_LEN) + q0 + w * 16 + n) * DH + g * 8;
  BFU qf[2];
#pragma unroll
  for (int cc = 0; cc < 2; ++cc) {
    float4 x = *(const float4*)(qg + 32 * cc);
    float4 y = *(const float4*)(qg + 32 * cc + 4);
    const float sc = 0.125f * LOG2E;
    qf[cc].q.x = pk2(x.x * sc, x.y * sc);
    qf[cc].q.y = pk2(x.z * sc, x.w * sc);
    qf[cc].q.z = pk2(y.x * sc, y.y * sc);
    qf[cc].q.w = pk2(y.z * sc, y.w * sc);
  }

  f32x4 acc[4] = {{0.f,0.f,0.f,0.f},{0.f,0.f,0.f,0.f},{0.f,0.f,0.f,0.f},{0.f,0.f,0.f,0.f}};
  float mrun[4] = {0.f, 0.f, 0.f, 0.f};
  float lrun[4] = {1.f, 1.f, 1.f, 1.f};

  const int sr = t >> 2;
  const int dc = (t & 3) * 16;
  const size_t kvbase = (size_t)(bh * S_LEN) * DH;

  for (int kt = 0; kt <= qt; ++kt) {
    __syncthreads();
    {
      const float* kg = K + kvbase + (size_t)(kt * 64 + sr) * DH + dc;
      float4 k0 = *(const float4*)(kg);
      float4 k1 = *(const float4*)(kg + 4);
      float4 k2 = *(const float4*)(kg + 8);
      float4 k3 = *(const float4*)(kg + 12);
      uint4 h0, h1;
      h0.x = pk2(k0.x, k0.y); h0.y = pk2(k0.z, k0.w);
      h0.z = pk2(k1.x, k1.y); h0.w = pk2(k1.z, k1.w);
      h1.x = pk2(k2.x, k2.y); h1.y = pk2(k2.z, k2.w);
      h1.z = pk2(k3.x, k3.y); h1.w = pk2(k3.z, k3.w);
      const int kbase = sr * 128 + dc * 2;
      const int ksw = (sr & 7) << 4;
      *(uint4*)(kb + ((kbase) ^ ksw)) = h0;
      *(uint4*)(kb + ((kbase + 16) ^ ksw)) = h1;

      const float* vg = V + kvbase + (size_t)(kt * 64 + sr) * DH + dc;
      float4 v0 = *(const float4*)(vg);
      float4 v1 = *(const float4*)(vg + 4);
      float4 v2 = *(const float4*)(vg + 8);
      float4 v3 = *(const float4*)(vg + 12);
      const int r2 = sr * 2;
#define VW(j, val) { const int d_ = dc + (j); \
  *(unsigned short*)(vb + ((d_ * 128 + r2) ^ ((d_ & 7) << 4))) = f2bf(val); }
      VW(0, v0.x) VW(1, v0.y) VW(2, v0.z) VW(3, v0.w)
      VW(4, v1.x) VW(5, v1.y) VW(6, v1.z) VW(7, v1.w)
      VW(8, v2.x) VW(9, v2.y) VW(10, v2.z) VW(11, v2.w)
      VW(12, v3.x) VW(13, v3.y) VW(14, v3.z) VW(15, v3.w)
#undef VW
    }
    __syncthreads();

    f32x4 sv[4] = {{0.f,0.f,0.f,0.f},{0.f,0.f,0.f,0.f},{0.f,0.f,0.f,0.f},{0.f,0.f,0.f,0.f}};
#pragma unroll
    for (int cc = 0; cc < 2; ++cc) {
#pragma unroll
      for (int nt = 0; nt < 4; ++nt) {
        const int kv = nt * 16 + n;
        BFU kf;
        kf.q = *(const uint4*)(kb + ((kv * 128 + g * 16 + cc * 64) ^ ((kv & 7) << 4)));
        sv[nt] = __builtin_amdgcn_mfma_f32_16x16x32_bf16(qf[cc].v, kf.v, sv[nt], 0, 0, 0);
      }
    }

    if (kt == qt) {
#pragma unroll
      for (int nt = 0; nt < 4; ++nt)
#pragma unroll
        for (int r = 0; r < 4; ++r)
          if (nt * 16 + n > w * 16 + g * 4 + r) sv[nt][r] = -1e9f;
    }

#pragma unroll
    for (int r = 0; r < 4; ++r) {
      float s0 = sv[0][r], s1 = sv[1][r], s2 = sv[2][r], s3 = sv[3][r];
      float mx = fmaxf(fmaxf(s0, s1), fmaxf(s2, s3));
#pragma unroll
      for (int off = 1; off < 16; off <<= 1) mx = fmaxf(mx, __shfl_xor(mx, off));
      const float mnew = fmaxf(mrun[r], mx);
      const float p0 = exp2f(s0 - mnew);
      const float p1 = exp2f(s1 - mnew);
      const float p2 = exp2f(s2 - mnew);
      const float p3 = exp2f(s3 - mnew);
      float sum = (p0 + p1) + (p2 + p3);
#pragma unroll
      for (int off = 1; off < 16; off <<= 1) sum += __shfl_xor(sum, off);
      const float scale = exp2f(mrun[r] - mnew);
      lrun[r] = lrun[r] * scale + sum;
      mrun[r] = mnew;
      acc[0][r] *= scale; acc[1][r] *= scale; acc[2][r] *= scale; acc[3][r] *= scale;
      const int row = g * 4 + r;
      const int rb = row * 128;
      const int sw = (row & 7) << 4;
      *(unsigned short*)(pb + ((rb + (0 * 16 + n) * 2) ^ sw)) = f2bf(p0);
      *(unsigned short*)(pb + ((rb + (1 * 16 + n) * 2) ^ sw)) = f2bf(p1);
      *(unsigned short*)(pb + ((rb + (2 * 16 + n) * 2) ^ sw)) = f2bf(p2);
      *(unsigned short*)(pb + ((rb + (3 * 16 + n) * 2) ^ sw)) = f2bf(p3);
    }

#pragma unroll
    for (int cc = 0; cc < 2; ++cc) {
      BFU pfr;
      pfr.q = *(const uint4*)(pb + ((n * 128 + g * 16 + cc * 64) ^ ((n & 7) << 4)));
#pragma unroll
      for (int nt = 0; nt < 4; ++nt) {
        const int d_ = nt * 16 + n;
        BFU vf;
        vf.q = *(const uint4*)(vb + ((d_ * 128 + g * 16 + cc * 64) ^ ((d_ & 7) << 4)));
        acc[nt] = __builtin_amdgcn_mfma_f32_16x16x32_bf16(pfr.v, vf.v, acc[nt], 0, 0, 0);
      }
    }
  }

#pragma unroll
  for (int r = 0; r < 4; ++r) {
    const float inv = 1.f / lrun[r];
    float* op = O + ((size_t)(bh * S_LEN) + q0 + w * 16 + g * 4 + r) * DH + n;
    op[0]  = acc[0][r] * inv;
    op[16] = acc[1][r] * inv;
    op[32] = acc[2][r] * inv;
    op[48] = acc[3][r] * inv;
  }
}

extern "C" void kernel_launch(void* const* d_in, const int* in_sizes, int n_in,
                              void* d_out, int out_size, void* d_ws, size_t ws_size,
                              hipStream_t stream) {
  const float* Q = (const float*)d_in[0];
  const float* K = (const float*)d_in[1];
  const float* V = (const float*)d_in[2];
  float* O = (float*)d_out;
  const size_t need_pack = (size_t)1024 * 8192 * 2;            // 16 MB tiles
  const size_t need_split = need_pack + (size_t)1984 * PSTRIDE; // + 18.3 MB partials
  if (ws_size >= need_split) {
    unsigned char* wsK = (unsigned char*)d_ws;
    unsigned char* wsVt = wsK + (size_t)1024 * 8192;
    unsigned char* pws = wsVt + (size_t)1024 * 8192;
    prepack<<<dim3(1024), dim3(256), 0, stream>>>(K, V, wsK, wsVt);
    fattn9<<<dim3(3040), dim3(64), 0, stream>>>(Q, wsK, wsVt, pws, O);
    combine<<<dim3(992), dim3(64), 0, stream>>>(pws, O);
  } else if (ws_size >= need_pack) {
    unsigned char* wsK = (unsigned char*)d_ws;
    unsigned char* wsVt = wsK + (size_t)1024 * 8192;
    prepack<<<dim3(1024), dim3(256), 0, stream>>>(K, V, wsK, wsVt);
    fattn8<<<dim3(2048), dim3(64), 0, stream>>>(Q, wsK, wsVt, O);
  } else {
    fattn_fb<<<dim3(1024), dim3(256), 0, stream>>>(Q, K, V, O);
  }
}

// Round 10
// 65.900 us; speedup vs baseline: 3.3029x; 3.3029x over previous
//
#include <hip/hip_runtime.h>

typedef __attribute__((ext_vector_type(8))) short bf16x8;
typedef __attribute__((ext_vector_type(4))) float f32x4;
typedef __attribute__((ext_vector_type(16))) float f32x16;

union BFU { uint4 q; bf16x8 v; };

__device__ __forceinline__ unsigned short f2bf(float f) {
  unsigned u = __float_as_uint(f);
  u += 0x7fff + ((u >> 16) & 1);
  return (unsigned short)(u >> 16);
}
__device__ __forceinline__ unsigned pk2(float a, float b) {
  return (unsigned)f2bf(a) | ((unsigned)f2bf(b) << 16);
}
__device__ __forceinline__ unsigned cvtpk(float lo, float hi) {
  unsigned d;
  asm("v_cvt_pk_bf16_f32 %0, %1, %2" : "=v"(d) : "v"(lo), "v"(hi));
  return d;
}
__device__ __forceinline__ float xhalf_sum(float x) {
  return x + __shfl_xor(x, 32);
}

#define S_LEN 2048
#define DH 64
#define LOG2E 1.4426950408889634f
#define PSTRIDE 9216   // bytes per partial: 64 lanes * 144B

// ---- pre-pass: fragment-major bf16 tiles (proven R7/R8) --------------------
__global__ __launch_bounds__(256) void prepack(const float* __restrict__ K,
                                               const float* __restrict__ V,
                                               unsigned char* __restrict__ wsK,
                                               unsigned char* __restrict__ wsVt) {
  const int t = threadIdx.x;
  const int bid = blockIdx.x;              // bh*32 + kt
  const size_t gbase = (size_t)bid * 4096;
  const int row = t & 63;
  const int j = t >> 6;                    // 0..3
  unsigned char* obK = wsK + (size_t)bid * 8192;
  unsigned char* obV = wsVt + (size_t)bid * 8192;
#pragma unroll
  for (int gg = 0; gg < 2; ++gg) {
    const int g = j + gg * 4;              // 0..7
    {
      const float* kg = K + gbase + (size_t)row * DH + g * 8;
      float4 x = *(const float4*)kg;
      float4 y = *(const float4*)(kg + 4);
      uint4 h;
      h.x = pk2(x.x, x.y); h.y = pk2(x.z, x.w);
      h.z = pk2(y.x, y.y); h.w = pk2(y.z, y.w);
      *(uint4*)(obK + g * 1024 + row * 16) = h;
    }
    {
      const float* vg = V + gbase + row;
      float v0 = vg[(size_t)(g * 8 + 0) * DH], v1 = vg[(size_t)(g * 8 + 1) * DH];
      float v2 = vg[(size_t)(g * 8 + 2) * DH], v3 = vg[(size_t)(g * 8 + 3) * DH];
      float v4 = vg[(size_t)(g * 8 + 4) * DH], v5 = vg[(size_t)(g * 8 + 5) * DH];
      float v6 = vg[(size_t)(g * 8 + 6) * DH], v7 = vg[(size_t)(g * 8 + 7) * DH];
      uint4 h;
      h.x = pk2(v0, v1); h.y = pk2(v2, v3);
      h.z = pk2(v4, v5); h.w = pk2(v6, v7);
      *(uint4*)(obV + g * 1024 + row * 16) = h;
    }
  }
}

// ---- split-K main: 1-wave blocks, fixed-m ghost softmax --------------------
// NO forced occupancy (R9 lesson: launch_bounds(64,4) -> VGPR=64 -> spill storm).
// Register diet instead: sacc[4] so the allocator can land <=128 naturally.
// grid = 32 bh * 95:  u<62: heavy (qt=63-(u>>1), part=u&1, kv-split);
//                     u>=62: light (qt=32-(u-62)), direct O write.
__global__ __launch_bounds__(64) void fattn10(const float* __restrict__ Q,
                                              const unsigned char* __restrict__ wsK,
                                              const unsigned char* __restrict__ wsVt,
                                              unsigned char* __restrict__ pws,
                                              float* __restrict__ O) {
  const int lane = threadIdx.x;
  const int c = lane & 31;
  const int hi = lane >> 5;

  const int bid = blockIdx.x;
  const int bh = bid & 31;
  const int u = bid >> 5;                  // 0..94, LPT (longest first)
  const bool heavy = (u < 62);
  const int qt = heavy ? (63 - (u >> 1)) : (32 - (u - 62));
  const int part = heavy ? (u & 1) : 0;

  // ---- Q fragments (B-operand: col=q=c, k=d), scale (1/8)*log2e ----
  const float* qrow = Q + ((size_t)(bh * S_LEN) + qt * 32 + c) * DH;
  BFU qf[4];
#pragma unroll
  for (int i = 0; i < 4; ++i) {
    const int d0 = i * 16 + hi * 8;
    float4 x = *(const float4*)(qrow + d0);
    float4 y = *(const float4*)(qrow + d0 + 4);
    const float sc = 0.125f * LOG2E;
    qf[i].q.x = pk2(x.x * sc, x.y * sc);
    qf[i].q.y = pk2(x.z * sc, x.w * sc);
    qf[i].q.z = pk2(y.x * sc, y.y * sc);
    qf[i].q.w = pk2(y.z * sc, y.w * sc);
  }

  f32x16 acc0, acc1;
#pragma unroll
  for (int r = 0; r < 16; ++r) { acc0[r] = 0.f; acc1[r] = 0.f; }
  float sacc[4] = {0.f, 0.f, 0.f, 0.f};    // denominator partials (reg diet)

  const unsigned char* tbK = wsK + (size_t)bh * 32 * 8192;
  const unsigned char* tbV = wsVt + (size_t)bh * 32 * 8192;
  const int fo = hi * 1024 + c * 16;

  const int NT = (qt + 1) >> 1;            // full 64-kv tiles
  const int last = qt >> 1;                // max tile index incl. tail
  const int NTH = NT - (NT >> 1);          // ceil(NT/2): part0 size
  const int t0 = (heavy && part == 1) ? NTH : 0;
  const int t1 = (heavy && part == 0) ? NTH : NT;
  const bool dotail = (!(qt & 1)) && (!heavy || part == 1);

  BFU kf0[4], kf1[4], vf0[4], vf1[4];
#define LOADK(tile_)                                                       \
  {                                                                        \
    const unsigned char* kb_ = tbK + (size_t)(tile_) * 8192;               \
    _Pragma("unroll")                                                      \
    for (int i = 0; i < 4; ++i) {                                          \
      kf0[i].q = *(const uint4*)(kb_ + i * 2048 + fo);                     \
      kf1[i].q = *(const uint4*)(kb_ + i * 2048 + fo + 512);               \
    }                                                                      \
  }
#define LOADV(tile_)                                                       \
  {                                                                        \
    const unsigned char* vb_ = tbV + (size_t)(tile_) * 8192;               \
    _Pragma("unroll")                                                      \
    for (int i = 0; i < 4; ++i) {                                          \
      vf0[i].q = *(const uint4*)(vb_ + i * 2048 + fo);                     \
      vf1[i].q = *(const uint4*)(vb_ + i * 2048 + fo + 512);               \
    }                                                                      \
  }
#define MAKEPF(dst, x0, x1, x2, x3, y0, y1, y2, y3)                  \
    {                                                                \
      unsigned a01 = cvtpk(x0, x1), a23 = cvtpk(x2, x3);             \
      unsigned b01 = cvtpk(y0, y1), b23 = cvtpk(y2, y3);             \
      asm("v_permlane32_swap_b32 %0, %1" : "+v"(a01), "+v"(b01));    \
      asm("v_permlane32_swap_b32 %0, %1" : "+v"(a23), "+v"(b23));    \
      (dst).q.x = a01; (dst).q.y = a23; (dst).q.z = b01; (dst).q.w = b23; \
    }

  LOADK(t0)
  LOADV(t0)

  for (int kt = t0; kt < t1; ++kt) {
    // ---- QK^T (swapped): S^T[kv][q] = mfma(A=K, B=Q) ----
    f32x16 st0, st1;
#pragma unroll
    for (int r = 0; r < 16; ++r) { st0[r] = 0.f; st1[r] = 0.f; }
    __builtin_amdgcn_s_setprio(1);
#pragma unroll
    for (int i = 0; i < 4; ++i) {
      st0 = __builtin_amdgcn_mfma_f32_32x32x16_bf16(kf0[i].v, qf[i].v, st0, 0, 0, 0);
      st1 = __builtin_amdgcn_mfma_f32_32x32x16_bf16(kf1[i].v, qf[i].v, st1, 0, 0, 0);
    }
    __builtin_amdgcn_s_setprio(0);

    if (kt + 1 <= last) LOADK(kt + 1)

    // odd qt: last full tile straddles the diagonal (always in part1/light)
    if ((qt & 1) && kt == NT - 1) {
#pragma unroll
      for (int r = 0; r < 16; ++r) {
        const int kvloc = (r & 3) + 8 * (r >> 2) + 4 * hi;
        if (kvloc > c) st1[r] = -1e9f;
      }
    }

    // ---- fixed-m ghost softmax: P = exp2(s); denominator deferred ----
#pragma unroll
    for (int r = 0; r < 16; ++r) { st0[r] = exp2f(st0[r]); st1[r] = exp2f(st1[r]); }
#pragma unroll
    for (int r = 0; r < 16; ++r) sacc[r & 3] += st0[r] + st1[r];

    BFU pf[4];
    MAKEPF(pf[0], st0[0], st0[1], st0[2], st0[3], st0[4], st0[5], st0[6], st0[7])
    MAKEPF(pf[1], st0[8], st0[9], st0[10], st0[11], st0[12], st0[13], st0[14], st0[15])
    MAKEPF(pf[2], st1[0], st1[1], st1[2], st1[3], st1[4], st1[5], st1[6], st1[7])
    MAKEPF(pf[3], st1[8], st1[9], st1[10], st1[11], st1[12], st1[13], st1[14], st1[15])

    __builtin_amdgcn_s_setprio(1);
#pragma unroll
    for (int kvt = 0; kvt < 4; ++kvt) {
      acc0 = __builtin_amdgcn_mfma_f32_32x32x16_bf16(vf0[kvt].v, pf[kvt].v, acc0, 0, 0, 0);
      acc1 = __builtin_amdgcn_mfma_f32_32x32x16_bf16(vf1[kvt].v, pf[kvt].v, acc1, 0, 0, 0);
    }
    __builtin_amdgcn_s_setprio(0);

    if (kt + 1 <= last) LOADV(kt + 1)
  }

  // ---- even qt: diagonal half-tile (kv 0..31 of tile 'last'), st0 only ----
  if (dotail) {
    f32x16 st0;
#pragma unroll
    for (int r = 0; r < 16; ++r) st0[r] = 0.f;
    __builtin_amdgcn_s_setprio(1);
#pragma unroll
    for (int i = 0; i < 4; ++i)
      st0 = __builtin_amdgcn_mfma_f32_32x32x16_bf16(kf0[i].v, qf[i].v, st0, 0, 0, 0);
    __builtin_amdgcn_s_setprio(0);
#pragma unroll
    for (int r = 0; r < 16; ++r) {
      const int kvloc = (r & 3) + 8 * (r >> 2) + 4 * hi;
      st0[r] = (kvloc > c) ? 0.f : exp2f(st0[r]);
    }
#pragma unroll
    for (int r = 0; r < 16; ++r) sacc[r & 3] += st0[r];
    BFU pf0, pf1;
    MAKEPF(pf0, st0[0], st0[1], st0[2], st0[3], st0[4], st0[5], st0[6], st0[7])
    MAKEPF(pf1, st0[8], st0[9], st0[10], st0[11], st0[12], st0[13], st0[14], st0[15])
    __builtin_amdgcn_s_setprio(1);
    acc0 = __builtin_amdgcn_mfma_f32_32x32x16_bf16(vf0[0].v, pf0.v, acc0, 0, 0, 0);
    acc0 = __builtin_amdgcn_mfma_f32_32x32x16_bf16(vf0[1].v, pf1.v, acc0, 0, 0, 0);
    acc1 = __builtin_amdgcn_mfma_f32_32x32x16_bf16(vf1[0].v, pf0.v, acc1, 0, 0, 0);
    acc1 = __builtin_amdgcn_mfma_f32_32x32x16_bf16(vf1[1].v, pf1.v, acc1, 0, 0, 0);
    __builtin_amdgcn_s_setprio(0);
  }
#undef MAKEPF
#undef LOADK
#undef LOADV

  // ---- per-lane denominator partial; ghost +1 added at the end ----
  const float lpart = (sacc[0] + sacc[1]) + (sacc[2] + sacc[3]);

  if (!heavy) {
    const float lrun = 1.f + xhalf_sum(lpart);
    const float inv = 1.f / lrun;
    float* orow = O + ((size_t)(bh * S_LEN) + qt * 32 + c) * DH;
#pragma unroll
    for (int k = 0; k < 4; ++k) {
      float4 o0, o1;
      o0.x = acc0[4 * k] * inv;     o0.y = acc0[4 * k + 1] * inv;
      o0.z = acc0[4 * k + 2] * inv; o0.w = acc0[4 * k + 3] * inv;
      o1.x = acc1[4 * k] * inv;     o1.y = acc1[4 * k + 1] * inv;
      o1.z = acc1[4 * k + 2] * inv; o1.w = acc1[4 * k + 3] * inv;
      *(float4*)(orow + 8 * k + 4 * hi) = o0;
      *(float4*)(orow + 32 + 8 * k + 4 * hi) = o1;
    }
  } else {
    // partial: pid = bh*62 + u; per lane 144B: acc0(64) acc1(64) l(4)
    unsigned char* base = pws + (size_t)(bh * 62 + u) * PSTRIDE + lane * 144;
#pragma unroll
    for (int k = 0; k < 4; ++k) {
      float4 a0, a1;
      a0.x = acc0[4 * k];     a0.y = acc0[4 * k + 1];
      a0.z = acc0[4 * k + 2]; a0.w = acc0[4 * k + 3];
      a1.x = acc1[4 * k];     a1.y = acc1[4 * k + 1];
      a1.z = acc1[4 * k + 2]; a1.w = acc1[4 * k + 3];
      *(float4*)(base + k * 16) = a0;
      *(float4*)(base + 64 + k * 16) = a1;
    }
    *(float*)(base + 128) = lpart;
  }
}

// ---- combine: O = (accA+accB) / (1 + lA + lB) ------------------------------
__global__ __launch_bounds__(64) void combine(const unsigned char* __restrict__ pws,
                                              float* __restrict__ O) {
  const int lane = threadIdx.x;
  const int c = lane & 31;
  const int hi = lane >> 5;
  const int bh = blockIdx.x & 31;
  const int j = blockIdx.x >> 5;       // 0..30 -> qt = 63-j
  const int qt = 63 - j;
  const unsigned char* p0 = pws + (size_t)(bh * 62 + 2 * j) * PSTRIDE + lane * 144;
  const unsigned char* p1 = p0 + PSTRIDE;

  float a0[16], a1[16];
#pragma unroll
  for (int k = 0; k < 4; ++k) {
    float4 x0 = *(const float4*)(p0 + k * 16);
    float4 y0 = *(const float4*)(p1 + k * 16);
    a0[4 * k] = x0.x + y0.x; a0[4 * k + 1] = x0.y + y0.y;
    a0[4 * k + 2] = x0.z + y0.z; a0[4 * k + 3] = x0.w + y0.w;
    float4 x1 = *(const float4*)(p0 + 64 + k * 16);
    float4 y1 = *(const float4*)(p1 + 64 + k * 16);
    a1[4 * k] = x1.x + y1.x; a1[4 * k + 1] = x1.y + y1.y;
    a1[4 * k + 2] = x1.z + y1.z; a1[4 * k + 3] = x1.w + y1.w;
  }
  const float lp = *(const float*)(p0 + 128) + *(const float*)(p1 + 128);
  const float lrun = 1.f + xhalf_sum(lp);
  const float inv = 1.f / lrun;
  float* orow = O + ((size_t)(bh * S_LEN) + qt * 32 + c) * DH;
#pragma unroll
  for (int k = 0; k < 4; ++k) {
    float4 o0, o1;
    o0.x = a0[4 * k] * inv;     o0.y = a0[4 * k + 1] * inv;
    o0.z = a0[4 * k + 2] * inv; o0.w = a0[4 * k + 3] * inv;
    o1.x = a1[4 * k] * inv;     o1.y = a1[4 * k + 1] * inv;
    o1.z = a1[4 * k + 2] * inv; o1.w = a1[4 * k + 3] * inv;
    *(float4*)(orow + 8 * k + 4 * hi) = o0;
    *(float4*)(orow + 32 + 8 * k + 4 * hi) = o1;
  }
}

// ---- mid-tier: R8 kernel (proven 49.7us) for 16MB <= ws < 35MB -------------
__global__ __launch_bounds__(64) void fattn8(const float* __restrict__ Q,
                                             const unsigned char* __restrict__ wsK,
                                             const unsigned char* __restrict__ wsVt,
                                             float* __restrict__ O) {
  const int lane = threadIdx.x;
  const int c = lane & 31;
  const int hi = lane >> 5;

  const int bid = blockIdx.x;
  const int bh = bid & 31;
  const int qt = 63 - (bid >> 5);

  const float* qrow = Q + ((size_t)(bh * S_LEN) + qt * 32 + c) * DH;
  BFU qf[4];
#pragma unroll
  for (int i = 0; i < 4; ++i) {
    const int d0 = i * 16 + hi * 8;
    float4 x = *(const float4*)(qrow + d0);
    float4 y = *(const float4*)(qrow + d0 + 4);
    const float sc = 0.125f * LOG2E;
    qf[i].q.x = pk2(x.x * sc, x.y * sc);
    qf[i].q.y = pk2(x.z * sc, x.w * sc);
    qf[i].q.z = pk2(y.x * sc, y.y * sc);
    qf[i].q.w = pk2(y.z * sc, y.w * sc);
  }

  f32x16 acc0, acc1;
#pragma unroll
  for (int r = 0; r < 16; ++r) { acc0[r] = 0.f; acc1[r] = 0.f; }
  float sacc[16];
#pragma unroll
  for (int r = 0; r < 16; ++r) sacc[r] = 0.f;

  const unsigned char* tbK = wsK + (size_t)bh * 32 * 8192;
  const unsigned char* tbV = wsVt + (size_t)bh * 32 * 8192;
  const int fo = hi * 1024 + c * 16;

  const int NT = (qt + 1) >> 1;
  const int last = qt >> 1;

  BFU kf0[4], kf1[4], vf0[4], vf1[4];
#define LOADK(tile_)                                                       \
  {                                                                        \
    const unsigned char* kb_ = tbK + (size_t)(tile_) * 8192;               \
    _Pragma("unroll")                                                      \
    for (int i = 0; i < 4; ++i) {                                          \
      kf0[i].q = *(const uint4*)(kb_ + i * 2048 + fo);                     \
      kf1[i].q = *(const uint4*)(kb_ + i * 2048 + fo + 512);               \
    }                                                                      \
  }
#define LOADV(tile_)                                                       \
  {                                                                        \
    const unsigned char* vb_ = tbV + (size_t)(tile_) * 8192;               \
    _Pragma("unroll")                                                      \
    for (int i = 0; i < 4; ++i) {                                          \
      vf0[i].q = *(const uint4*)(vb_ + i * 2048 + fo);                     \
      vf1[i].q = *(const uint4*)(vb_ + i * 2048 + fo + 512);               \
    }                                                                      \
  }
#define QK8(D0, D1)                                                        \
  {                                                                        \
    _Pragma("unroll")                                                      \
    for (int r = 0; r < 16; ++r) { (D0)[r] = 0.f; (D1)[r] = 0.f; }         \
    __builtin_amdgcn_s_setprio(1);                                         \
    _Pragma("unroll")                                                      \
    for (int i = 0; i < 4; ++i) {                                          \
      (D0) = __builtin_amdgcn_mfma_f32_32x32x16_bf16(kf0[i].v, qf[i].v, (D0), 0, 0, 0); \
      (D1) = __builtin_amdgcn_mfma_f32_32x32x16_bf16(kf1[i].v, qf[i].v, (D1), 0, 0, 0); \
    }                                                                      \
    __builtin_amdgcn_s_setprio(0);                                         \
  }
#define MAKEPF(dst, x0, x1, x2, x3, y0, y1, y2, y3)                  \
    {                                                                \
      unsigned a01 = cvtpk(x0, x1), a23 = cvtpk(x2, x3);             \
      unsigned b01 = cvtpk(y0, y1), b23 = cvtpk(y2, y3);             \
      asm("v_permlane32_swap_b32 %0, %1" : "+v"(a01), "+v"(b01));    \
      asm("v_permlane32_swap_b32 %0, %1" : "+v"(a23), "+v"(b23));    \
      (dst).q.x = a01; (dst).q.y = a23; (dst).q.z = b01; (dst).q.w = b23; \
    }
#define BODY(S0, S1, N0, N1, KT)                                           \
  {                                                                        \
    if ((KT) + 1 < NT) QK8(N0, N1)                                         \
    if ((KT) + 2 <= last) LOADK((KT) + 2)                                  \
    if ((qt & 1) && (KT) == NT - 1) {                                      \
      _Pragma("unroll")                                                    \
      for (int r = 0; r < 16; ++r) {                                       \
        const int kvloc = (r & 3) + 8 * (r >> 2) + 4 * hi;                 \
        if (kvloc > c) (S1)[r] = -1e9f;                                    \
      }                                                                    \
    }                                                                      \
    _Pragma("unroll")                                                      \
    for (int r = 0; r < 16; ++r) { (S0)[r] = exp2f((S0)[r]); (S1)[r] = exp2f((S1)[r]); } \
    _Pragma("unroll")                                                      \
    for (int r = 0; r < 16; ++r) sacc[r] += (S0)[r] + (S1)[r];             \
    BFU pf[4];                                                             \
    MAKEPF(pf[0], (S0)[0], (S0)[1], (S0)[2], (S0)[3], (S0)[4], (S0)[5], (S0)[6], (S0)[7])  \
    MAKEPF(pf[1], (S0)[8], (S0)[9], (S0)[10], (S0)[11], (S0)[12], (S0)[13], (S0)[14], (S0)[15]) \
    MAKEPF(pf[2], (S1)[0], (S1)[1], (S1)[2], (S1)[3], (S1)[4], (S1)[5], (S1)[6], (S1)[7])  \
    MAKEPF(pf[3], (S1)[8], (S1)[9], (S1)[10], (S1)[11], (S1)[12], (S1)[13], (S1)[14], (S1)[15]) \
    __builtin_amdgcn_s_setprio(1);                                         \
    _Pragma("unroll")                                                      \
    for (int kvt = 0; kvt < 4; ++kvt) {                                    \
      acc0 = __builtin_amdgcn_mfma_f32_32x32x16_bf16(vf0[kvt].v, pf[kvt].v, acc0, 0, 0, 0); \
      acc1 = __builtin_amdgcn_mfma_f32_32x32x16_bf16(vf1[kvt].v, pf[kvt].v, acc1, 0, 0, 0); \
    }                                                                      \
    __builtin_amdgcn_s_setprio(0);                                         \
    if ((KT) + 1 <= last) LOADV((KT) + 1)                                  \
  }

  LOADK(0)
  LOADV(0)

  f32x16 stA0, stA1, stB0, stB1;
  QK8(stA0, stA1)
  if (1 <= last) LOADK(1)

  int kt = 0;
  for (; kt + 1 < NT; kt += 2) {
    BODY(stA0, stA1, stB0, stB1, kt)
    BODY(stB0, stB1, stA0, stA1, kt + 1)
  }
  if (kt < NT) BODY(stA0, stA1, stB0, stB1, kt)

  if (!(qt & 1)) {
    f32x16 st0;
#pragma unroll
    for (int r = 0; r < 16; ++r) st0[r] = 0.f;
    __builtin_amdgcn_s_setprio(1);
#pragma unroll
    for (int i = 0; i < 4; ++i)
      st0 = __builtin_amdgcn_mfma_f32_32x32x16_bf16(kf0[i].v, qf[i].v, st0, 0, 0, 0);
    __builtin_amdgcn_s_setprio(0);
#pragma unroll
    for (int r = 0; r < 16; ++r) {
      const int kvloc = (r & 3) + 8 * (r >> 2) + 4 * hi;
      st0[r] = (kvloc > c) ? 0.f : exp2f(st0[r]);
    }
#pragma unroll
    for (int r = 0; r < 16; ++r) sacc[r] += st0[r];
    BFU pf0, pf1;
    MAKEPF(pf0, st0[0], st0[1], st0[2], st0[3], st0[4], st0[5], st0[6], st0[7])
    MAKEPF(pf1, st0[8], st0[9], st0[10], st0[11], st0[12], st0[13], st0[14], st0[15])
    __builtin_amdgcn_s_setprio(1);
    acc0 = __builtin_amdgcn_mfma_f32_32x32x16_bf16(vf0[0].v, pf0.v, acc0, 0, 0, 0);
    acc0 = __builtin_amdgcn_mfma_f32_32x32x16_bf16(vf0[1].v, pf1.v, acc0, 0, 0, 0);
    acc1 = __builtin_amdgcn_mfma_f32_32x32x16_bf16(vf1[0].v, pf0.v, acc1, 0, 0, 0);
    acc1 = __builtin_amdgcn_mfma_f32_32x32x16_bf16(vf1[1].v, pf1.v, acc1, 0, 0, 0);
    __builtin_amdgcn_s_setprio(0);
  }
#undef BODY
#undef MAKEPF
#undef QK8
#undef LOADK
#undef LOADV

#pragma unroll
  for (int off = 8; off >= 1; off >>= 1)
#pragma unroll
    for (int r = 0; r < 8; ++r)
      if (r < off) sacc[r] += sacc[r + off];
  const float lrun = 1.f + xhalf_sum(sacc[0]);

  const float inv = 1.f / lrun;
  float* orow = O + ((size_t)(bh * S_LEN) + qt * 32 + c) * DH;
#pragma unroll
  for (int k = 0; k < 4; ++k) {
    float4 o0, o1;
    o0.x = acc0[4 * k] * inv;     o0.y = acc0[4 * k + 1] * inv;
    o0.z = acc0[4 * k + 2] * inv; o0.w = acc0[4 * k + 3] * inv;
    o1.x = acc1[4 * k] * inv;     o1.y = acc1[4 * k + 1] * inv;
    o1.z = acc1[4 * k + 2] * inv; o1.w = acc1[4 * k + 3] * inv;
    *(float4*)(orow + 8 * k + 4 * hi) = o0;
    *(float4*)(orow + 32 + 8 * k + 4 * hi) = o1;
  }
}

// ---------------- fallback (R2 staging kernel) if ws too small ----------------
__global__ __launch_bounds__(256) void fattn_fb(const float* __restrict__ Q,
                                                const float* __restrict__ K,
                                                const float* __restrict__ V,
                                                float* __restrict__ O) {
  __shared__ __align__(16) unsigned char lds[24 * 1024];
  unsigned char* kb = lds;
  unsigned char* vb = lds + 8192;
  const int t = threadIdx.x;
  const int lane = t & 63;
  const int w = t >> 6;
  const int g = lane >> 4;
  const int n = lane & 15;
  unsigned char* pb = lds + 16384 + w * 2048;

  const int bid = blockIdx.x;
  const int bh = bid & 31;
  const int qt = bid >> 5;
  const int q0 = qt * 64;

  const float* qg = Q + ((size_t)(bh * S_LEN) + q0 + w * 16 + n) * DH + g * 8;
  BFU qf[2];
#pragma unroll
  for (int cc = 0; cc < 2; ++cc) {
    float4 x = *(const float4*)(qg + 32 * cc);
    float4 y = *(const float4*)(qg + 32 * cc + 4);
    const float sc = 0.125f * LOG2E;
    qf[cc].q.x = pk2(x.x * sc, x.y * sc);
    qf[cc].q.y = pk2(x.z * sc, x.w * sc);
    qf[cc].q.z = pk2(y.x * sc, y.y * sc);
    qf[cc].q.w = pk2(y.z * sc, y.w * sc);
  }

  f32x4 acc[4] = {{0.f,0.f,0.f,0.f},{0.f,0.f,0.f,0.f},{0.f,0.f,0.f,0.f},{0.f,0.f,0.f,0.f}};
  float mrun[4] = {0.f, 0.f, 0.f, 0.f};
  float lrun[4] = {1.f, 1.f, 1.f, 1.f};

  const int sr = t >> 2;
  const int dc = (t & 3) * 16;
  const size_t kvbase = (size_t)(bh * S_LEN) * DH;

  for (int kt = 0; kt <= qt; ++kt) {
    __syncthreads();
    {
      const float* kg = K + kvbase + (size_t)(kt * 64 + sr) * DH + dc;
      float4 k0 = *(const float4*)(kg);
      float4 k1 = *(const float4*)(kg + 4);
      float4 k2 = *(const float4*)(kg + 8);
      float4 k3 = *(const float4*)(kg + 12);
      uint4 h0, h1;
      h0.x = pk2(k0.x, k0.y); h0.y = pk2(k0.z, k0.w);
      h0.z = pk2(k1.x, k1.y); h0.w = pk2(k1.z, k1.w);
      h1.x = pk2(k2.x, k2.y); h1.y = pk2(k2.z, k2.w);
      h1.z = pk2(k3.x, k3.y); h1.w = pk2(k3.z, k3.w);
      const int kbase = sr * 128 + dc * 2;
      const int ksw = (sr & 7) << 4;
      *(uint4*)(kb + ((kbase) ^ ksw)) = h0;
      *(uint4*)(kb + ((kbase + 16) ^ ksw)) = h1;

      const float* vg = V + kvbase + (size_t)(kt * 64 + sr) * DH + dc;
      float4 v0 = *(const float4*)(vg);
      float4 v1 = *(const float4*)(vg + 4);
      float4 v2 = *(const float4*)(vg + 8);
      float4 v3 = *(const float4*)(vg + 12);
      const int r2 = sr * 2;
#define VW(j, val) { const int d_ = dc + (j); \
  *(unsigned short*)(vb + ((d_ * 128 + r2) ^ ((d_ & 7) << 4))) = f2bf(val); }
      VW(0, v0.x) VW(1, v0.y) VW(2, v0.z) VW(3, v0.w)
      VW(4, v1.x) VW(5, v1.y) VW(6, v1.z) VW(7, v1.w)
      VW(8, v2.x) VW(9, v2.y) VW(10, v2.z) VW(11, v2.w)
      VW(12, v3.x) VW(13, v3.y) VW(14, v3.z) VW(15, v3.w)
#undef VW
    }
    __syncthreads();

    f32x4 sv[4] = {{0.f,0.f,0.f,0.f},{0.f,0.f,0.f,0.f},{0.f,0.f,0.f,0.f},{0.f,0.f,0.f,0.f}};
#pragma unroll
    for (int cc = 0; cc < 2; ++cc) {
#pragma unroll
      for (int nt = 0; nt < 4; ++nt) {
        const int kv = nt * 16 + n;
        BFU kf;
        kf.q = *(const uint4*)(kb + ((kv * 128 + g * 16 + cc * 64) ^ ((kv & 7) << 4)));
        sv[nt] = __builtin_amdgcn_mfma_f32_16x16x32_bf16(qf[cc].v, kf.v, sv[nt], 0, 0, 0);
      }
    }

    if (kt == qt) {
#pragma unroll
      for (int nt = 0; nt < 4; ++nt)
#pragma unroll
        for (int r = 0; r < 4; ++r)
          if (nt * 16 + n > w * 16 + g * 4 + r) sv[nt][r] = -1e9f;
    }

#pragma unroll
    for (int r = 0; r < 4; ++r) {
      float s0 = sv[0][r], s1 = sv[1][r], s2 = sv[2][r], s3 = sv[3][r];
      float mx = fmaxf(fmaxf(s0, s1), fmaxf(s2, s3));
#pragma unroll
      for (int off = 1; off < 16; off <<= 1) mx = fmaxf(mx, __shfl_xor(mx, off));
      const float mnew = fmaxf(mrun[r], mx);
      const float p0 = exp2f(s0 - mnew);
      const float p1 = exp2f(s1 - mnew);
      const float p2 = exp2f(s2 - mnew);
      const float p3 = exp2f(s3 - mnew);
      float sum = (p0 + p1) + (p2 + p3);
#pragma unroll
      for (int off = 1; off < 16; off <<= 1) sum += __shfl_xor(sum, off);
      const float scale = exp2f(mrun[r] - mnew);
      lrun[r] = lrun[r] * scale + sum;
      mrun[r] = mnew;
      acc[0][r] *= scale; acc[1][r] *= scale; acc[2][r] *= scale; acc[3][r] *= scale;
      const int row = g * 4 + r;
      const int rb = row * 128;
      const int sw = (row & 7) << 4;
      *(unsigned short*)(pb + ((rb + (0 * 16 + n) * 2) ^ sw)) = f2bf(p0);
      *(unsigned short*)(pb + ((rb + (1 * 16 + n) * 2) ^ sw)) = f2bf(p1);
      *(unsigned short*)(pb + ((rb + (2 * 16 + n) * 2) ^ sw)) = f2bf(p2);
      *(unsigned short*)(pb + ((rb + (3 * 16 + n) * 2) ^ sw)) = f2bf(p3);
    }

#pragma unroll
    for (int cc = 0; cc < 2; ++cc) {
      BFU pfr;
      pfr.q = *(const uint4*)(pb + ((n * 128 + g * 16 + cc * 64) ^ ((n & 7) << 4)));
#pragma unroll
      for (int nt = 0; nt < 4; ++nt) {
        const int d_ = nt * 16 + n;
        BFU vf;
        vf.q = *(const uint4*)(vb + ((d_ * 128 + g * 16 + cc * 64) ^ ((d_ & 7) << 4)));
        acc[nt] = __builtin_amdgcn_mfma_f32_16x16x32_bf16(pfr.v, vf.v, acc[nt], 0, 0, 0);
      }
    }
  }

#pragma unroll
  for (int r = 0; r < 4; ++r) {
    const float inv = 1.f / lrun[r];
    float* op = O + ((size_t)(bh * S_LEN) + q0 + w * 16 + g * 4 + r) * DH + n;
    op[0]  = acc[0][r] * inv;
    op[16] = acc[1][r] * inv;
    op[32] = acc[2][r] * inv;
    op[48] = acc[3][r] * inv;
  }
}

extern "C" void kernel_launch(void* const* d_in, const int* in_sizes, int n_in,
                              void* d_out, int out_size, void* d_ws, size_t ws_size,
                              hipStream_t stream) {
  const float* Q = (const float*)d_in[0];
  const float* K = (const float*)d_in[1];
  const float* V = (const float*)d_in[2];
  float* O = (float*)d_out;
  const size_t need_pack = (size_t)1024 * 8192 * 2;            // 16 MB tiles
  const size_t need_split = need_pack + (size_t)1984 * PSTRIDE; // + 18.3 MB partials
  if (ws_size >= need_split) {
    unsigned char* wsK = (unsigned char*)d_ws;
    unsigned char* wsVt = wsK + (size_t)1024 * 8192;
    unsigned char* pws = wsVt + (size_t)1024 * 8192;
    prepack<<<dim3(1024), dim3(256), 0, stream>>>(K, V, wsK, wsVt);
    fattn10<<<dim3(3040), dim3(64), 0, stream>>>(Q, wsK, wsVt, pws, O);
    combine<<<dim3(992), dim3(64), 0, stream>>>(pws, O);
  } else if (ws_size >= need_pack) {
    unsigned char* wsK = (unsigned char*)d_ws;
    unsigned char* wsVt = wsK + (size_t)1024 * 8192;
    prepack<<<dim3(1024), dim3(256), 0, stream>>>(K, V, wsK, wsVt);
    fattn8<<<dim3(2048), dim3(64), 0, stream>>>(Q, wsK, wsVt, O);
  } else {
    fattn_fb<<<dim3(1024), dim3(256), 0, stream>>>(Q, K, V, O);
  }
}

// Round 11
// 65.105 us; speedup vs baseline: 3.3433x; 1.0122x over previous
//
#include <hip/hip_runtime.h>

typedef __attribute__((ext_vector_type(8))) short bf16x8;
typedef __attribute__((ext_vector_type(4))) float f32x4;
typedef __attribute__((ext_vector_type(16))) float f32x16;

union BFU { uint4 q; bf16x8 v; };

__device__ __forceinline__ unsigned short f2bf(float f) {
  unsigned u = __float_as_uint(f);
  u += 0x7fff + ((u >> 16) & 1);
  return (unsigned short)(u >> 16);
}
__device__ __forceinline__ unsigned pk2(float a, float b) {
  return (unsigned)f2bf(a) | ((unsigned)f2bf(b) << 16);
}
__device__ __forceinline__ unsigned cvtpk(float lo, float hi) {
  unsigned d;
  asm("v_cvt_pk_bf16_f32 %0, %1, %2" : "=v"(d) : "v"(lo), "v"(hi));
  return d;
}
__device__ __forceinline__ float xhalf_sum(float x) {
  return x + __shfl_xor(x, 32);
}

#define S_LEN 2048
#define DH 64
#define LOG2E 1.4426950408889634f
#define PSTRIDE 9216   // bytes per partial: 64 lanes * 144B

// ---- pre-pass: fragment-major bf16 tiles (proven R7/R8) --------------------
__global__ __launch_bounds__(256) void prepack(const float* __restrict__ K,
                                               const float* __restrict__ V,
                                               unsigned char* __restrict__ wsK,
                                               unsigned char* __restrict__ wsVt) {
  const int t = threadIdx.x;
  const int bid = blockIdx.x;              // bh*32 + kt
  const size_t gbase = (size_t)bid * 4096;
  const int row = t & 63;
  const int j = t >> 6;                    // 0..3
  unsigned char* obK = wsK + (size_t)bid * 8192;
  unsigned char* obV = wsVt + (size_t)bid * 8192;
#pragma unroll
  for (int gg = 0; gg < 2; ++gg) {
    const int g = j + gg * 4;              // 0..7
    {
      const float* kg = K + gbase + (size_t)row * DH + g * 8;
      float4 x = *(const float4*)kg;
      float4 y = *(const float4*)(kg + 4);
      uint4 h;
      h.x = pk2(x.x, x.y); h.y = pk2(x.z, x.w);
      h.z = pk2(y.x, y.y); h.w = pk2(y.z, y.w);
      *(uint4*)(obK + g * 1024 + row * 16) = h;
    }
    {
      const float* vg = V + gbase + row;
      float v0 = vg[(size_t)(g * 8 + 0) * DH], v1 = vg[(size_t)(g * 8 + 1) * DH];
      float v2 = vg[(size_t)(g * 8 + 2) * DH], v3 = vg[(size_t)(g * 8 + 3) * DH];
      float v4 = vg[(size_t)(g * 8 + 4) * DH], v5 = vg[(size_t)(g * 8 + 5) * DH];
      float v6 = vg[(size_t)(g * 8 + 6) * DH], v7 = vg[(size_t)(g * 8 + 7) * DH];
      uint4 h;
      h.x = pk2(v0, v1); h.y = pk2(v2, v3);
      h.z = pk2(v4, v5); h.w = pk2(v6, v7);
      *(uint4*)(obV + g * 1024 + row * 16) = h;
    }
  }
}

// ---- split-K main + 2-stage SW pipeline (R8 BODY + R10 partitioning) -------
// grid = 32 bh * 95:  u<62: heavy (qt=63-(u>>1) in [33,63], part=u&1);
//                     u>=62: light (qt=32-(u-62) in [0,32]), direct O write.
__global__ __launch_bounds__(64) void fattn11(const float* __restrict__ Q,
                                              const unsigned char* __restrict__ wsK,
                                              const unsigned char* __restrict__ wsVt,
                                              unsigned char* __restrict__ pws,
                                              float* __restrict__ O) {
  const int lane = threadIdx.x;
  const int c = lane & 31;
  const int hi = lane >> 5;

  const int bid = blockIdx.x;
  const int bh = bid & 31;
  const int u = bid >> 5;                  // 0..94, LPT (longest first)
  const bool heavy = (u < 62);
  const int qt = heavy ? (63 - (u >> 1)) : (32 - (u - 62));
  const int part = heavy ? (u & 1) : 0;

  // ---- Q fragments (B-operand: col=q=c, k=d), scale (1/8)*log2e ----
  const float* qrow = Q + ((size_t)(bh * S_LEN) + qt * 32 + c) * DH;
  BFU qf[4];
#pragma unroll
  for (int i = 0; i < 4; ++i) {
    const int d0 = i * 16 + hi * 8;
    float4 x = *(const float4*)(qrow + d0);
    float4 y = *(const float4*)(qrow + d0 + 4);
    const float sc = 0.125f * LOG2E;
    qf[i].q.x = pk2(x.x * sc, x.y * sc);
    qf[i].q.y = pk2(x.z * sc, x.w * sc);
    qf[i].q.z = pk2(y.x * sc, y.y * sc);
    qf[i].q.w = pk2(y.z * sc, y.w * sc);
  }

  f32x16 acc0, acc1;
#pragma unroll
  for (int r = 0; r < 16; ++r) { acc0[r] = 0.f; acc1[r] = 0.f; }
  float sacc[4] = {0.f, 0.f, 0.f, 0.f};

  const unsigned char* tbK = wsK + (size_t)bh * 32 * 8192;
  const unsigned char* tbV = wsVt + (size_t)bh * 32 * 8192;
  const int fo = hi * 1024 + c * 16;

  const int NT = (qt + 1) >> 1;            // full 64-kv tiles
  const int last = qt >> 1;                // max tile index incl. tail
  const int NTH = NT - (NT >> 1);          // ceil(NT/2): part0 size
  const int t0 = (heavy && part == 1) ? NTH : 0;
  const int t1 = (heavy && part == 0) ? NTH : NT;
  // part0 never computes the tail and never needs tiles >= t1:
  const int lastL = (heavy && part == 0) ? (t1 - 1) : last;
  const bool dotail = (!(qt & 1)) && (!heavy || part == 1);

  BFU kf0[4], kf1[4], vf0[4], vf1[4];
#define LOADK(tile_)                                                       \
  {                                                                        \
    const unsigned char* kb_ = tbK + (size_t)(tile_) * 8192;               \
    _Pragma("unroll")                                                      \
    for (int i = 0; i < 4; ++i) {                                          \
      kf0[i].q = *(const uint4*)(kb_ + i * 2048 + fo);                     \
      kf1[i].q = *(const uint4*)(kb_ + i * 2048 + fo + 512);               \
    }                                                                      \
  }
#define LOADV(tile_)                                                       \
  {                                                                        \
    const unsigned char* vb_ = tbV + (size_t)(tile_) * 8192;               \
    _Pragma("unroll")                                                      \
    for (int i = 0; i < 4; ++i) {                                          \
      vf0[i].q = *(const uint4*)(vb_ + i * 2048 + fo);                     \
      vf1[i].q = *(const uint4*)(vb_ + i * 2048 + fo + 512);               \
    }                                                                      \
  }
#define QK8(D0, D1)                                                        \
  {                                                                        \
    _Pragma("unroll")                                                      \
    for (int r = 0; r < 16; ++r) { (D0)[r] = 0.f; (D1)[r] = 0.f; }         \
    __builtin_amdgcn_s_setprio(1);                                         \
    _Pragma("unroll")                                                      \
    for (int i = 0; i < 4; ++i) {                                          \
      (D0) = __builtin_amdgcn_mfma_f32_32x32x16_bf16(kf0[i].v, qf[i].v, (D0), 0, 0, 0); \
      (D1) = __builtin_amdgcn_mfma_f32_32x32x16_bf16(kf1[i].v, qf[i].v, (D1), 0, 0, 0); \
    }                                                                      \
    __builtin_amdgcn_s_setprio(0);                                         \
  }
#define MAKEPF(dst, x0, x1, x2, x3, y0, y1, y2, y3)                  \
    {                                                                \
      unsigned a01 = cvtpk(x0, x1), a23 = cvtpk(x2, x3);             \
      unsigned b01 = cvtpk(y0, y1), b23 = cvtpk(y2, y3);             \
      asm("v_permlane32_swap_b32 %0, %1" : "+v"(a01), "+v"(b01));    \
      asm("v_permlane32_swap_b32 %0, %1" : "+v"(a23), "+v"(b23));    \
      (dst).q.x = a01; (dst).q.y = a23; (dst).q.z = b01; (dst).q.w = b23; \
    }
// one pipeline stage: consume (S0,S1)=scores(KT); produce (N0,N1)=scores(KT+1)
#define BODY(S0, S1, N0, N1, KT)                                           \
  {                                                                        \
    if ((KT) + 1 < t1) QK8(N0, N1)          /* overlaps exp/PV below */    \
    if ((KT) + 2 <= lastL) LOADK((KT) + 2)                                 \
    if ((qt & 1) && (KT) == NT - 1) {                                      \
      _Pragma("unroll")                                                    \
      for (int r = 0; r < 16; ++r) {                                       \
        const int kvloc = (r & 3) + 8 * (r >> 2) + 4 * hi;                 \
        if (kvloc > c) (S1)[r] = -1e9f;                                    \
      }                                                                    \
    }                                                                      \
    _Pragma("unroll")                                                      \
    for (int r = 0; r < 16; ++r) { (S0)[r] = exp2f((S0)[r]); (S1)[r] = exp2f((S1)[r]); } \
    _Pragma("unroll")                                                      \
    for (int r = 0; r < 16; ++r) sacc[r & 3] += (S0)[r] + (S1)[r];         \
    BFU pf[4];                                                             \
    MAKEPF(pf[0], (S0)[0], (S0)[1], (S0)[2], (S0)[3], (S0)[4], (S0)[5], (S0)[6], (S0)[7])  \
    MAKEPF(pf[1], (S0)[8], (S0)[9], (S0)[10], (S0)[11], (S0)[12], (S0)[13], (S0)[14], (S0)[15]) \
    MAKEPF(pf[2], (S1)[0], (S1)[1], (S1)[2], (S1)[3], (S1)[4], (S1)[5], (S1)[6], (S1)[7])  \
    MAKEPF(pf[3], (S1)[8], (S1)[9], (S1)[10], (S1)[11], (S1)[12], (S1)[13], (S1)[14], (S1)[15]) \
    __builtin_amdgcn_s_setprio(1);                                         \
    _Pragma("unroll")                                                      \
    for (int kvt = 0; kvt < 4; ++kvt) {                                    \
      acc0 = __builtin_amdgcn_mfma_f32_32x32x16_bf16(vf0[kvt].v, pf[kvt].v, acc0, 0, 0, 0); \
      acc1 = __builtin_amdgcn_mfma_f32_32x32x16_bf16(vf1[kvt].v, pf[kvt].v, acc1, 0, 0, 0); \
    }                                                                      \
    __builtin_amdgcn_s_setprio(0);                                         \
    if ((KT) + 1 <= lastL) LOADV((KT) + 1)                                 \
  }

  LOADK(t0)
  LOADV(t0)

  f32x16 stA0, stA1, stB0, stB1;
  // prologue: scores(t0) -> A (harmless for empty ranges; tail recomputes)
  QK8(stA0, stA1)
  if (t0 + 1 <= lastL) LOADK(t0 + 1)

  int kt = t0;
  for (; kt + 1 < t1; kt += 2) {
    BODY(stA0, stA1, stB0, stB1, kt)
    BODY(stB0, stB1, stA0, stA1, kt + 1)
  }
  if (kt < t1) BODY(stA0, stA1, stB0, stB1, kt)

  // ---- even qt: diagonal half-tile (kv 0..31 of tile 'last'), st0 only ----
  if (dotail) {
    f32x16 st0;
#pragma unroll
    for (int r = 0; r < 16; ++r) st0[r] = 0.f;
    __builtin_amdgcn_s_setprio(1);
#pragma unroll
    for (int i = 0; i < 4; ++i)
      st0 = __builtin_amdgcn_mfma_f32_32x32x16_bf16(kf0[i].v, qf[i].v, st0, 0, 0, 0);
    __builtin_amdgcn_s_setprio(0);
#pragma unroll
    for (int r = 0; r < 16; ++r) {
      const int kvloc = (r & 3) + 8 * (r >> 2) + 4 * hi;
      st0[r] = (kvloc > c) ? 0.f : exp2f(st0[r]);
    }
#pragma unroll
    for (int r = 0; r < 16; ++r) sacc[r & 3] += st0[r];
    BFU pf0, pf1;
    MAKEPF(pf0, st0[0], st0[1], st0[2], st0[3], st0[4], st0[5], st0[6], st0[7])
    MAKEPF(pf1, st0[8], st0[9], st0[10], st0[11], st0[12], st0[13], st0[14], st0[15])
    __builtin_amdgcn_s_setprio(1);
    acc0 = __builtin_amdgcn_mfma_f32_32x32x16_bf16(vf0[0].v, pf0.v, acc0, 0, 0, 0);
    acc0 = __builtin_amdgcn_mfma_f32_32x32x16_bf16(vf0[1].v, pf1.v, acc0, 0, 0, 0);
    acc1 = __builtin_amdgcn_mfma_f32_32x32x16_bf16(vf1[0].v, pf0.v, acc1, 0, 0, 0);
    acc1 = __builtin_amdgcn_mfma_f32_32x32x16_bf16(vf1[1].v, pf1.v, acc1, 0, 0, 0);
    __builtin_amdgcn_s_setprio(0);
  }
#undef BODY
#undef MAKEPF
#undef QK8
#undef LOADK
#undef LOADV

  const float lpart = (sacc[0] + sacc[1]) + (sacc[2] + sacc[3]);

  if (!heavy) {
    const float lrun = 1.f + xhalf_sum(lpart);
    const float inv = 1.f / lrun;
    float* orow = O + ((size_t)(bh * S_LEN) + qt * 32 + c) * DH;
#pragma unroll
    for (int k = 0; k < 4; ++k) {
      float4 o0, o1;
      o0.x = acc0[4 * k] * inv;     o0.y = acc0[4 * k + 1] * inv;
      o0.z = acc0[4 * k + 2] * inv; o0.w = acc0[4 * k + 3] * inv;
      o1.x = acc1[4 * k] * inv;     o1.y = acc1[4 * k + 1] * inv;
      o1.z = acc1[4 * k + 2] * inv; o1.w = acc1[4 * k + 3] * inv;
      *(float4*)(orow + 8 * k + 4 * hi) = o0;
      *(float4*)(orow + 32 + 8 * k + 4 * hi) = o1;
    }
  } else {
    // partial: pid = bh*62 + u; per lane 144B: acc0(64) acc1(64) l(4)
    unsigned char* base = pws + (size_t)(bh * 62 + u) * PSTRIDE + lane * 144;
#pragma unroll
    for (int k = 0; k < 4; ++k) {
      float4 a0, a1;
      a0.x = acc0[4 * k];     a0.y = acc0[4 * k + 1];
      a0.z = acc0[4 * k + 2]; a0.w = acc0[4 * k + 3];
      a1.x = acc1[4 * k];     a1.y = acc1[4 * k + 1];
      a1.z = acc1[4 * k + 2]; a1.w = acc1[4 * k + 3];
      *(float4*)(base + k * 16) = a0;
      *(float4*)(base + 64 + k * 16) = a1;
    }
    *(float*)(base + 128) = lpart;
  }
}

// ---- combine: O = (accA+accB) / (1 + lA + lB) ------------------------------
__global__ __launch_bounds__(64) void combine(const unsigned char* __restrict__ pws,
                                              float* __restrict__ O) {
  const int lane = threadIdx.x;
  const int c = lane & 31;
  const int hi = lane >> 5;
  const int bh = blockIdx.x & 31;
  const int j = blockIdx.x >> 5;       // 0..30 -> qt = 63-j
  const int qt = 63 - j;
  const unsigned char* p0 = pws + (size_t)(bh * 62 + 2 * j) * PSTRIDE + lane * 144;
  const unsigned char* p1 = p0 + PSTRIDE;

  float a0[16], a1[16];
#pragma unroll
  for (int k = 0; k < 4; ++k) {
    float4 x0 = *(const float4*)(p0 + k * 16);
    float4 y0 = *(const float4*)(p1 + k * 16);
    a0[4 * k] = x0.x + y0.x; a0[4 * k + 1] = x0.y + y0.y;
    a0[4 * k + 2] = x0.z + y0.z; a0[4 * k + 3] = x0.w + y0.w;
    float4 x1 = *(const float4*)(p0 + 64 + k * 16);
    float4 y1 = *(const float4*)(p1 + 64 + k * 16);
    a1[4 * k] = x1.x + y1.x; a1[4 * k + 1] = x1.y + y1.y;
    a1[4 * k + 2] = x1.z + y1.z; a1[4 * k + 3] = x1.w + y1.w;
  }
  const float lp = *(const float*)(p0 + 128) + *(const float*)(p1 + 128);
  const float lrun = 1.f + xhalf_sum(lp);
  const float inv = 1.f / lrun;
  float* orow = O + ((size_t)(bh * S_LEN) + qt * 32 + c) * DH;
#pragma unroll
  for (int k = 0; k < 4; ++k) {
    float4 o0, o1;
    o0.x = a0[4 * k] * inv;     o0.y = a0[4 * k + 1] * inv;
    o0.z = a0[4 * k + 2] * inv; o0.w = a0[4 * k + 3] * inv;
    o1.x = a1[4 * k] * inv;     o1.y = a1[4 * k + 1] * inv;
    o1.z = a1[4 * k + 2] * inv; o1.w = a1[4 * k + 3] * inv;
    *(float4*)(orow + 8 * k + 4 * hi) = o0;
    *(float4*)(orow + 32 + 8 * k + 4 * hi) = o1;
  }
}

// ---- mid-tier: R8 kernel (proven 49.7us) for 16MB <= ws < 35MB -------------
__global__ __launch_bounds__(64) void fattn8(const float* __restrict__ Q,
                                             const unsigned char* __restrict__ wsK,
                                             const unsigned char* __restrict__ wsVt,
                                             float* __restrict__ O) {
  const int lane = threadIdx.x;
  const int c = lane & 31;
  const int hi = lane >> 5;

  const int bid = blockIdx.x;
  const int bh = bid & 31;
  const int qt = 63 - (bid >> 5);

  const float* qrow = Q + ((size_t)(bh * S_LEN) + qt * 32 + c) * DH;
  BFU qf[4];
#pragma unroll
  for (int i = 0; i < 4; ++i) {
    const int d0 = i * 16 + hi * 8;
    float4 x = *(const float4*)(qrow + d0);
    float4 y = *(const float4*)(qrow + d0 + 4);
    const float sc = 0.125f * LOG2E;
    qf[i].q.x = pk2(x.x * sc, x.y * sc);
    qf[i].q.y = pk2(x.z * sc, x.w * sc);
    qf[i].q.z = pk2(y.x * sc, y.y * sc);
    qf[i].q.w = pk2(y.z * sc, y.w * sc);
  }

  f32x16 acc0, acc1;
#pragma unroll
  for (int r = 0; r < 16; ++r) { acc0[r] = 0.f; acc1[r] = 0.f; }
  float sacc[16];
#pragma unroll
  for (int r = 0; r < 16; ++r) sacc[r] = 0.f;

  const unsigned char* tbK = wsK + (size_t)bh * 32 * 8192;
  const unsigned char* tbV = wsVt + (size_t)bh * 32 * 8192;
  const int fo = hi * 1024 + c * 16;

  const int NT = (qt + 1) >> 1;
  const int last = qt >> 1;

  BFU kf0[4], kf1[4], vf0[4], vf1[4];
#define LOADK(tile_)                                                       \
  {                                                                        \
    const unsigned char* kb_ = tbK + (size_t)(tile_) * 8192;               \
    _Pragma("unroll")                                                      \
    for (int i = 0; i < 4; ++i) {                                          \
      kf0[i].q = *(const uint4*)(kb_ + i * 2048 + fo);                     \
      kf1[i].q = *(const uint4*)(kb_ + i * 2048 + fo + 512);               \
    }                                                                      \
  }
#define LOADV(tile_)                                                       \
  {                                                                        \
    const unsigned char* vb_ = tbV + (size_t)(tile_) * 8192;               \
    _Pragma("unroll")                                                      \
    for (int i = 0; i < 4; ++i) {                                          \
      vf0[i].q = *(const uint4*)(vb_ + i * 2048 + fo);                     \
      vf1[i].q = *(const uint4*)(vb_ + i * 2048 + fo + 512);               \
    }                                                                      \
  }
#define QK8(D0, D1)                                                        \
  {                                                                        \
    _Pragma("unroll")                                                      \
    for (int r = 0; r < 16; ++r) { (D0)[r] = 0.f; (D1)[r] = 0.f; }         \
    __builtin_amdgcn_s_setprio(1);                                         \
    _Pragma("unroll")                                                      \
    for (int i = 0; i < 4; ++i) {                                          \
      (D0) = __builtin_amdgcn_mfma_f32_32x32x16_bf16(kf0[i].v, qf[i].v, (D0), 0, 0, 0); \
      (D1) = __builtin_amdgcn_mfma_f32_32x32x16_bf16(kf1[i].v, qf[i].v, (D1), 0, 0, 0); \
    }                                                                      \
    __builtin_amdgcn_s_setprio(0);                                         \
  }
#define MAKEPF(dst, x0, x1, x2, x3, y0, y1, y2, y3)                  \
    {                                                                \
      unsigned a01 = cvtpk(x0, x1), a23 = cvtpk(x2, x3);             \
      unsigned b01 = cvtpk(y0, y1), b23 = cvtpk(y2, y3);             \
      asm("v_permlane32_swap_b32 %0, %1" : "+v"(a01), "+v"(b01));    \
      asm("v_permlane32_swap_b32 %0, %1" : "+v"(a23), "+v"(b23));    \
      (dst).q.x = a01; (dst).q.y = a23; (dst).q.z = b01; (dst).q.w = b23; \
    }
#define BODY(S0, S1, N0, N1, KT)                                           \
  {                                                                        \
    if ((KT) + 1 < NT) QK8(N0, N1)                                         \
    if ((KT) + 2 <= last) LOADK((KT) + 2)                                  \
    if ((qt & 1) && (KT) == NT - 1) {                                      \
      _Pragma("unroll")                                                    \
      for (int r = 0; r < 16; ++r) {                                       \
        const int kvloc = (r & 3) + 8 * (r >> 2) + 4 * hi;                 \
        if (kvloc > c) (S1)[r] = -1e9f;                                    \
      }                                                                    \
    }                                                                      \
    _Pragma("unroll")                                                      \
    for (int r = 0; r < 16; ++r) { (S0)[r] = exp2f((S0)[r]); (S1)[r] = exp2f((S1)[r]); } \
    _Pragma("unroll")                                                      \
    for (int r = 0; r < 16; ++r) sacc[r] += (S0)[r] + (S1)[r];             \
    BFU pf[4];                                                             \
    MAKEPF(pf[0], (S0)[0], (S0)[1], (S0)[2], (S0)[3], (S0)[4], (S0)[5], (S0)[6], (S0)[7])  \
    MAKEPF(pf[1], (S0)[8], (S0)[9], (S0)[10], (S0)[11], (S0)[12], (S0)[13], (S0)[14], (S0)[15]) \
    MAKEPF(pf[2], (S1)[0], (S1)[1], (S1)[2], (S1)[3], (S1)[4], (S1)[5], (S1)[6], (S1)[7])  \
    MAKEPF(pf[3], (S1)[8], (S1)[9], (S1)[10], (S1)[11], (S1)[12], (S1)[13], (S1)[14], (S1)[15]) \
    __builtin_amdgcn_s_setprio(1);                                         \
    _Pragma("unroll")                                                      \
    for (int kvt = 0; kvt < 4; ++kvt) {                                    \
      acc0 = __builtin_amdgcn_mfma_f32_32x32x16_bf16(vf0[kvt].v, pf[kvt].v, acc0, 0, 0, 0); \
      acc1 = __builtin_amdgcn_mfma_f32_32x32x16_bf16(vf1[kvt].v, pf[kvt].v, acc1, 0, 0, 0); \
    }                                                                      \
    __builtin_amdgcn_s_setprio(0);                                         \
    if ((KT) + 1 <= last) LOADV((KT) + 1)                                  \
  }

  LOADK(0)
  LOADV(0)

  f32x16 stA0, stA1, stB0, stB1;
  QK8(stA0, stA1)
  if (1 <= last) LOADK(1)

  int kt = 0;
  for (; kt + 1 < NT; kt += 2) {
    BODY(stA0, stA1, stB0, stB1, kt)
    BODY(stB0, stB1, stA0, stA1, kt + 1)
  }
  if (kt < NT) BODY(stA0, stA1, stB0, stB1, kt)

  if (!(qt & 1)) {
    f32x16 st0;
#pragma unroll
    for (int r = 0; r < 16; ++r) st0[r] = 0.f;
    __builtin_amdgcn_s_setprio(1);
#pragma unroll
    for (int i = 0; i < 4; ++i)
      st0 = __builtin_amdgcn_mfma_f32_32x32x16_bf16(kf0[i].v, qf[i].v, st0, 0, 0, 0);
    __builtin_amdgcn_s_setprio(0);
#pragma unroll
    for (int r = 0; r < 16; ++r) {
      const int kvloc = (r & 3) + 8 * (r >> 2) + 4 * hi;
      st0[r] = (kvloc > c) ? 0.f : exp2f(st0[r]);
    }
#pragma unroll
    for (int r = 0; r < 16; ++r) sacc[r] += st0[r];
    BFU pf0, pf1;
    MAKEPF(pf0, st0[0], st0[1], st0[2], st0[3], st0[4], st0[5], st0[6], st0[7])
    MAKEPF(pf1, st0[8], st0[9], st0[10], st0[11], st0[12], st0[13], st0[14], st0[15])
    __builtin_amdgcn_s_setprio(1);
    acc0 = __builtin_amdgcn_mfma_f32_32x32x16_bf16(vf0[0].v, pf0.v, acc0, 0, 0, 0);
    acc0 = __builtin_amdgcn_mfma_f32_32x32x16_bf16(vf0[1].v, pf1.v, acc0, 0, 0, 0);
    acc1 = __builtin_amdgcn_mfma_f32_32x32x16_bf16(vf1[0].v, pf0.v, acc1, 0, 0, 0);
    acc1 = __builtin_amdgcn_mfma_f32_32x32x16_bf16(vf1[1].v, pf1.v, acc1, 0, 0, 0);
    __builtin_amdgcn_s_setprio(0);
  }
#undef BODY
#undef MAKEPF
#undef QK8
#undef LOADK
#undef LOADV

#pragma unroll
  for (int off = 8; off >= 1; off >>= 1)
#pragma unroll
    for (int r = 0; r < 8; ++r)
      if (r < off) sacc[r] += sacc[r + off];
  const float lrun = 1.f + xhalf_sum(sacc[0]);

  const float inv = 1.f / lrun;
  float* orow = O + ((size_t)(bh * S_LEN) + qt * 32 + c) * DH;
#pragma unroll
  for (int k = 0; k < 4; ++k) {
    float4 o0, o1;
    o0.x = acc0[4 * k] * inv;     o0.y = acc0[4 * k + 1] * inv;
    o0.z = acc0[4 * k + 2] * inv; o0.w = acc0[4 * k + 3] * inv;
    o1.x = acc1[4 * k] * inv;     o1.y = acc1[4 * k + 1] * inv;
    o1.z = acc1[4 * k + 2] * inv; o1.w = acc1[4 * k + 3] * inv;
    *(float4*)(orow + 8 * k + 4 * hi) = o0;
    *(float4*)(orow + 32 + 8 * k + 4 * hi) = o1;
  }
}

// ---------------- fallback (R2 staging kernel) if ws too small ----------------
__global__ __launch_bounds__(256) void fattn_fb(const float* __restrict__ Q,
                                                const float* __restrict__ K,
                                                const float* __restrict__ V,
                                                float* __restrict__ O) {
  __shared__ __align__(16) unsigned char lds[24 * 1024];
  unsigned char* kb = lds;
  unsigned char* vb = lds + 8192;
  const int t = threadIdx.x;
  const int lane = t & 63;
  const int w = t >> 6;
  const int g = lane >> 4;
  const int n = lane & 15;
  unsigned char* pb = lds + 16384 + w * 2048;

  const int bid = blockIdx.x;
  const int bh = bid & 31;
  const int qt = bid >> 5;
  const int q0 = qt * 64;

  const float* qg = Q + ((size_t)(bh * S_LEN) + q0 + w * 16 + n) * DH + g * 8;
  BFU qf[2];
#pragma unroll
  for (int cc = 0; cc < 2; ++cc) {
    float4 x = *(const float4*)(qg + 32 * cc);
    float4 y = *(const float4*)(qg + 32 * cc + 4);
    const float sc = 0.125f * LOG2E;
    qf[cc].q.x = pk2(x.x * sc, x.y * sc);
    qf[cc].q.y = pk2(x.z * sc, x.w * sc);
    qf[cc].q.z = pk2(y.x * sc, y.y * sc);
    qf[cc].q.w = pk2(y.z * sc, y.w * sc);
  }

  f32x4 acc[4] = {{0.f,0.f,0.f,0.f},{0.f,0.f,0.f,0.f},{0.f,0.f,0.f,0.f},{0.f,0.f,0.f,0.f}};
  float mrun[4] = {0.f, 0.f, 0.f, 0.f};
  float lrun[4] = {1.f, 1.f, 1.f, 1.f};

  const int sr = t >> 2;
  const int dc = (t & 3) * 16;
  const size_t kvbase = (size_t)(bh * S_LEN) * DH;

  for (int kt = 0; kt <= qt; ++kt) {
    __syncthreads();
    {
      const float* kg = K + kvbase + (size_t)(kt * 64 + sr) * DH + dc;
      float4 k0 = *(const float4*)(kg);
      float4 k1 = *(const float4*)(kg + 4);
      float4 k2 = *(const float4*)(kg + 8);
      float4 k3 = *(const float4*)(kg + 12);
      uint4 h0, h1;
      h0.x = pk2(k0.x, k0.y); h0.y = pk2(k0.z, k0.w);
      h0.z = pk2(k1.x, k1.y); h0.w = pk2(k1.z, k1.w);
      h1.x = pk2(k2.x, k2.y); h1.y = pk2(k2.z, k2.w);
      h1.z = pk2(k3.x, k3.y); h1.w = pk2(k3.z, k3.w);
      const int kbase = sr * 128 + dc * 2;
      const int ksw = (sr & 7) << 4;
      *(uint4*)(kb + ((kbase) ^ ksw)) = h0;
      *(uint4*)(kb + ((kbase + 16) ^ ksw)) = h1;

      const float* vg = V + kvbase + (size_t)(kt * 64 + sr) * DH + dc;
      float4 v0 = *(const float4*)(vg);
      float4 v1 = *(const float4*)(vg + 4);
      float4 v2 = *(const float4*)(vg + 8);
      float4 v3 = *(const float4*)(vg + 12);
      const int r2 = sr * 2;
#define VW(j, val) { const int d_ = dc + (j); \
  *(unsigned short*)(vb + ((d_ * 128 + r2) ^ ((d_ & 7) << 4))) = f2bf(val); }
      VW(0, v0.x) VW(1, v0.y) VW(2, v0.z) VW(3, v0.w)
      VW(4, v1.x) VW(5, v1.y) VW(6, v1.z) VW(7, v1.w)
      VW(8, v2.x) VW(9, v2.y) VW(10, v2.z) VW(11, v2.w)
      VW(12, v3.x) VW(13, v3.y) VW(14, v3.z) VW(15, v3.w)
#undef VW
    }
    __syncthreads();

    f32x4 sv[4] = {{0.f,0.f,0.f,0.f},{0.f,0.f,0.f,0.f},{0.f,0.f,0.f,0.f},{0.f,0.f,0.f,0.f}};
#pragma unroll
    for (int cc = 0; cc < 2; ++cc) {
#pragma unroll
      for (int nt = 0; nt < 4; ++nt) {
        const int kv = nt * 16 + n;
        BFU kf;
        kf.q = *(const uint4*)(kb + ((kv * 128 + g * 16 + cc * 64) ^ ((kv & 7) << 4)));
        sv[nt] = __builtin_amdgcn_mfma_f32_16x16x32_bf16(qf[cc].v, kf.v, sv[nt], 0, 0, 0);
      }
    }

    if (kt == qt) {
#pragma unroll
      for (int nt = 0; nt < 4; ++nt)
#pragma unroll
        for (int r = 0; r < 4; ++r)
          if (nt * 16 + n > w * 16 + g * 4 + r) sv[nt][r] = -1e9f;
    }

#pragma unroll
    for (int r = 0; r < 4; ++r) {
      float s0 = sv[0][r], s1 = sv[1][r], s2 = sv[2][r], s3 = sv[3][r];
      float mx = fmaxf(fmaxf(s0, s1), fmaxf(s2, s3));
#pragma unroll
      for (int off = 1; off < 16; off <<= 1) mx = fmaxf(mx, __shfl_xor(mx, off));
      const float mnew = fmaxf(mrun[r], mx);
      const float p0 = exp2f(s0 - mnew);
      const float p1 = exp2f(s1 - mnew);
      const float p2 = exp2f(s2 - mnew);
      const float p3 = exp2f(s3 - mnew);
      float sum = (p0 + p1) + (p2 + p3);
#pragma unroll
      for (int off = 1; off < 16; off <<= 1) sum += __shfl_xor(sum, off);
      const float scale = exp2f(mrun[r] - mnew);
      lrun[r] = lrun[r] * scale + sum;
      mrun[r] = mnew;
      acc[0][r] *= scale; acc[1][r] *= scale; acc[2][r] *= scale; acc[3][r] *= scale;
      const int row = g * 4 + r;
      const int rb = row * 128;
      const int sw = (row & 7) << 4;
      *(unsigned short*)(pb + ((rb + (0 * 16 + n) * 2) ^ sw)) = f2bf(p0);
      *(unsigned short*)(pb + ((rb + (1 * 16 + n) * 2) ^ sw)) = f2bf(p1);
      *(unsigned short*)(pb + ((rb + (2 * 16 + n) * 2) ^ sw)) = f2bf(p2);
      *(unsigned short*)(pb + ((rb + (3 * 16 + n) * 2) ^ sw)) = f2bf(p3);
    }

#pragma unroll
    for (int cc = 0; cc < 2; ++cc) {
      BFU pfr;
      pfr.q = *(const uint4*)(pb + ((n * 128 + g * 16 + cc * 64) ^ ((n & 7) << 4)));
#pragma unroll
      for (int nt = 0; nt < 4; ++nt) {
        const int d_ = nt * 16 + n;
        BFU vf;
        vf.q = *(const uint4*)(vb + ((d_ * 128 + g * 16 + cc * 64) ^ ((d_ & 7) << 4)));
        acc[nt] = __builtin_amdgcn_mfma_f32_16x16x32_bf16(pfr.v, vf.v, acc[nt], 0, 0, 0);
      }
    }
  }

#pragma unroll
  for (int r = 0; r < 4; ++r) {
    const float inv = 1.f / lrun[r];
    float* op = O + ((size_t)(bh * S_LEN) + q0 + w * 16 + g * 4 + r) * DH + n;
    op[0]  = acc[0][r] * inv;
    op[16] = acc[1][r] * inv;
    op[32] = acc[2][r] * inv;
    op[48] = acc[3][r] * inv;
  }
}

extern "C" void kernel_launch(void* const* d_in, const int* in_sizes, int n_in,
                              void* d_out, int out_size, void* d_ws, size_t ws_size,
                              hipStream_t stream) {
  const float* Q = (const float*)d_in[0];
  const float* K = (const float*)d_in[1];
  const float* V = (const float*)d_in[2];
  float* O = (float*)d_out;
  const size_t need_pack = (size_t)1024 * 8192 * 2;            // 16 MB tiles
  const size_t need_split = need_pack + (size_t)1984 * PSTRIDE; // + 18.3 MB partials
  if (ws_size >= need_split) {
    unsigned char* wsK = (unsigned char*)d_ws;
    unsigned char* wsVt = wsK + (size_t)1024 * 8192;
    unsigned char* pws = wsVt + (size_t)1024 * 8192;
    prepack<<<dim3(1024), dim3(256), 0, stream>>>(K, V, wsK, wsVt);
    fattn11<<<dim3(3040), dim3(64), 0, stream>>>(Q, wsK, wsVt, pws, O);
    combine<<<dim3(992), dim3(64), 0, stream>>>(pws, O);
  } else if (ws_size >= need_pack) {
    unsigned char* wsK = (unsigned char*)d_ws;
    unsigned char* wsVt = wsK + (size_t)1024 * 8192;
    prepack<<<dim3(1024), dim3(256), 0, stream>>>(K, V, wsK, wsVt);
    fattn8<<<dim3(2048), dim3(64), 0, stream>>>(Q, wsK, wsVt, O);
  } else {
    fattn_fb<<<dim3(1024), dim3(256), 0, stream>>>(Q, K, V, O);
  }
}

// Round 12
// 62.925 us; speedup vs baseline: 3.4591x; 1.0346x over previous
//
#include <hip/hip_runtime.h>

typedef __attribute__((ext_vector_type(8))) short bf16x8;
typedef __attribute__((ext_vector_type(4))) float f32x4;
typedef __attribute__((ext_vector_type(16))) float f32x16;

union BFU { uint4 q; bf16x8 v; };

__device__ __forceinline__ unsigned short f2bf(float f) {
  unsigned u = __float_as_uint(f);
  u += 0x7fff + ((u >> 16) & 1);
  return (unsigned short)(u >> 16);
}
__device__ __forceinline__ unsigned pk2(float a, float b) {
  return (unsigned)f2bf(a) | ((unsigned)f2bf(b) << 16);
}
__device__ __forceinline__ unsigned cvtpk(float lo, float hi) {
  unsigned d;
  asm("v_cvt_pk_bf16_f32 %0, %1, %2" : "=v"(d) : "v"(lo), "v"(hi));
  return d;
}
__device__ __forceinline__ float xhalf_sum(float x) {
  return x + __shfl_xor(x, 32);
}

#define S_LEN 2048
#define DH 64
#define LOG2E 1.4426950408889634f
#define PSTRIDE 9216   // bytes per partial: 64 lanes * 144B

// LPT schedule: 95 chunks per bh sorted by DESCENDING size (R11 lesson: the
// late-arriving size-16 light blocks created a synchronized second round).
// code = qt<<1 | part; heavy <=> qt >= 33.
__device__ __constant__ unsigned char SCHED[95] = {
  126,127,124,122, 64, 62,                      // size 16
  125,123,120,121,118,119,116,114, 60, 58,      // 15
  117,115,112,113,110,111,108,106, 56, 54,      // 14
  109,107,104,105,102,103,100, 98, 52, 50,      // 13
  101, 99, 96, 97, 94, 95, 92, 90, 48, 46,      // 12
   93, 91, 88, 89, 86, 87, 84, 82, 44, 42,      // 11
   85, 83, 80, 81, 78, 79, 76, 74, 40, 38,      // 10
   77, 75, 72, 73, 70, 71, 68, 66, 36, 34,      // 9
   69, 67, 32, 30,                              // 8
   28, 26, 24, 22, 20, 18, 16, 14, 12, 10,      // 7..5
    8,  6,  4,  2,  0                           // 4..0
};

// ---- pre-pass: fragment-major bf16 tiles (proven R7/R8) --------------------
__global__ __launch_bounds__(256) void prepack(const float* __restrict__ K,
                                               const float* __restrict__ V,
                                               unsigned char* __restrict__ wsK,
                                               unsigned char* __restrict__ wsVt) {
  const int t = threadIdx.x;
  const int bid = blockIdx.x;              // bh*32 + kt
  const size_t gbase = (size_t)bid * 4096;
  const int row = t & 63;
  const int j = t >> 6;                    // 0..3
  unsigned char* obK = wsK + (size_t)bid * 8192;
  unsigned char* obV = wsVt + (size_t)bid * 8192;
#pragma unroll
  for (int gg = 0; gg < 2; ++gg) {
    const int g = j + gg * 4;              // 0..7
    {
      const float* kg = K + gbase + (size_t)row * DH + g * 8;
      float4 x = *(const float4*)kg;
      float4 y = *(const float4*)(kg + 4);
      uint4 h;
      h.x = pk2(x.x, x.y); h.y = pk2(x.z, x.w);
      h.z = pk2(y.x, y.y); h.w = pk2(y.z, y.w);
      *(uint4*)(obK + g * 1024 + row * 16) = h;
    }
    {
      const float* vg = V + gbase + row;
      float v0 = vg[(size_t)(g * 8 + 0) * DH], v1 = vg[(size_t)(g * 8 + 1) * DH];
      float v2 = vg[(size_t)(g * 8 + 2) * DH], v3 = vg[(size_t)(g * 8 + 3) * DH];
      float v4 = vg[(size_t)(g * 8 + 4) * DH], v5 = vg[(size_t)(g * 8 + 5) * DH];
      float v6 = vg[(size_t)(g * 8 + 6) * DH], v7 = vg[(size_t)(g * 8 + 7) * DH];
      uint4 h;
      h.x = pk2(v0, v1); h.y = pk2(v2, v3);
      h.z = pk2(v4, v5); h.w = pk2(v6, v7);
      *(uint4*)(obV + g * 1024 + row * 16) = h;
    }
  }
}

// ---- split-K main + 2-stage SW pipeline + LPT-desc launch order ------------
__global__ __launch_bounds__(64) void fattn12(const float* __restrict__ Q,
                                              const unsigned char* __restrict__ wsK,
                                              const unsigned char* __restrict__ wsVt,
                                              unsigned char* __restrict__ pws,
                                              float* __restrict__ O) {
  const int lane = threadIdx.x;
  const int c = lane & 31;
  const int hi = lane >> 5;

  const int bid = blockIdx.x;
  const int bh = bid & 31;
  const int u = bid >> 5;                  // 0..94, size-descending order
  const int code = SCHED[u];
  const int qt = code >> 1;
  const int part = code & 1;
  const bool heavy = (qt >= 33);

  // ---- Q fragments (B-operand: col=q=c, k=d), scale (1/8)*log2e ----
  const float* qrow = Q + ((size_t)(bh * S_LEN) + qt * 32 + c) * DH;
  BFU qf[4];
#pragma unroll
  for (int i = 0; i < 4; ++i) {
    const int d0 = i * 16 + hi * 8;
    float4 x = *(const float4*)(qrow + d0);
    float4 y = *(const float4*)(qrow + d0 + 4);
    const float sc = 0.125f * LOG2E;
    qf[i].q.x = pk2(x.x * sc, x.y * sc);
    qf[i].q.y = pk2(x.z * sc, x.w * sc);
    qf[i].q.z = pk2(y.x * sc, y.y * sc);
    qf[i].q.w = pk2(y.z * sc, y.w * sc);
  }

  f32x16 acc0, acc1;
#pragma unroll
  for (int r = 0; r < 16; ++r) { acc0[r] = 0.f; acc1[r] = 0.f; }
  float sacc[4] = {0.f, 0.f, 0.f, 0.f};

  const unsigned char* tbK = wsK + (size_t)bh * 32 * 8192;
  const unsigned char* tbV = wsVt + (size_t)bh * 32 * 8192;
  const int fo = hi * 1024 + c * 16;

  const int NT = (qt + 1) >> 1;            // full 64-kv tiles
  const int last = qt >> 1;                // max tile index incl. tail
  const int NTH = NT - (NT >> 1);          // ceil(NT/2): part0 size
  const int t0 = (heavy && part == 1) ? NTH : 0;
  const int t1 = (heavy && part == 0) ? NTH : NT;
  const int lastL = (heavy && part == 0) ? (t1 - 1) : last;
  const bool dotail = (!(qt & 1)) && (!heavy || part == 1);

  BFU kf0[4], kf1[4], vf0[4], vf1[4];
#define LOADK(tile_)                                                       \
  {                                                                        \
    const unsigned char* kb_ = tbK + (size_t)(tile_) * 8192;               \
    _Pragma("unroll")                                                      \
    for (int i = 0; i < 4; ++i) {                                          \
      kf0[i].q = *(const uint4*)(kb_ + i * 2048 + fo);                     \
      kf1[i].q = *(const uint4*)(kb_ + i * 2048 + fo + 512);               \
    }                                                                      \
  }
#define LOADV(tile_)                                                       \
  {                                                                        \
    const unsigned char* vb_ = tbV + (size_t)(tile_) * 8192;               \
    _Pragma("unroll")                                                      \
    for (int i = 0; i < 4; ++i) {                                          \
      vf0[i].q = *(const uint4*)(vb_ + i * 2048 + fo);                     \
      vf1[i].q = *(const uint4*)(vb_ + i * 2048 + fo + 512);               \
    }                                                                      \
  }
#define QK8(D0, D1)                                                        \
  {                                                                        \
    _Pragma("unroll")                                                      \
    for (int r = 0; r < 16; ++r) { (D0)[r] = 0.f; (D1)[r] = 0.f; }         \
    __builtin_amdgcn_s_setprio(1);                                         \
    _Pragma("unroll")                                                      \
    for (int i = 0; i < 4; ++i) {                                          \
      (D0) = __builtin_amdgcn_mfma_f32_32x32x16_bf16(kf0[i].v, qf[i].v, (D0), 0, 0, 0); \
      (D1) = __builtin_amdgcn_mfma_f32_32x32x16_bf16(kf1[i].v, qf[i].v, (D1), 0, 0, 0); \
    }                                                                      \
    __builtin_amdgcn_s_setprio(0);                                         \
  }
#define MAKEPF(dst, x0, x1, x2, x3, y0, y1, y2, y3)                  \
    {                                                                \
      unsigned a01 = cvtpk(x0, x1), a23 = cvtpk(x2, x3);             \
      unsigned b01 = cvtpk(y0, y1), b23 = cvtpk(y2, y3);             \
      asm("v_permlane32_swap_b32 %0, %1" : "+v"(a01), "+v"(b01));    \
      asm("v_permlane32_swap_b32 %0, %1" : "+v"(a23), "+v"(b23));    \
      (dst).q.x = a01; (dst).q.y = a23; (dst).q.z = b01; (dst).q.w = b23; \
    }
// one pipeline stage: consume (S0,S1)=scores(KT); produce (N0,N1)=scores(KT+1)
#define BODY(S0, S1, N0, N1, KT)                                           \
  {                                                                        \
    if ((KT) + 1 < t1) QK8(N0, N1)          /* overlaps exp/PV below */    \
    if ((KT) + 2 <= lastL) LOADK((KT) + 2)                                 \
    if ((qt & 1) && (KT) == NT - 1) {                                      \
      _Pragma("unroll")                                                    \
      for (int r = 0; r < 16; ++r) {                                       \
        const int kvloc = (r & 3) + 8 * (r >> 2) + 4 * hi;                 \
        if (kvloc > c) (S1)[r] = -1e9f;                                    \
      }                                                                    \
    }                                                                      \
    _Pragma("unroll")                                                      \
    for (int r = 0; r < 16; ++r) { (S0)[r] = exp2f((S0)[r]); (S1)[r] = exp2f((S1)[r]); } \
    _Pragma("unroll")                                                      \
    for (int r = 0; r < 16; ++r) sacc[r & 3] += (S0)[r] + (S1)[r];         \
    BFU pf[4];                                                             \
    MAKEPF(pf[0], (S0)[0], (S0)[1], (S0)[2], (S0)[3], (S0)[4], (S0)[5], (S0)[6], (S0)[7])  \
    MAKEPF(pf[1], (S0)[8], (S0)[9], (S0)[10], (S0)[11], (S0)[12], (S0)[13], (S0)[14], (S0)[15]) \
    MAKEPF(pf[2], (S1)[0], (S1)[1], (S1)[2], (S1)[3], (S1)[4], (S1)[5], (S1)[6], (S1)[7])  \
    MAKEPF(pf[3], (S1)[8], (S1)[9], (S1)[10], (S1)[11], (S1)[12], (S1)[13], (S1)[14], (S1)[15]) \
    __builtin_amdgcn_s_setprio(1);                                         \
    _Pragma("unroll")                                                      \
    for (int kvt = 0; kvt < 4; ++kvt) {                                    \
      acc0 = __builtin_amdgcn_mfma_f32_32x32x16_bf16(vf0[kvt].v, pf[kvt].v, acc0, 0, 0, 0); \
      acc1 = __builtin_amdgcn_mfma_f32_32x32x16_bf16(vf1[kvt].v, pf[kvt].v, acc1, 0, 0, 0); \
    }                                                                      \
    __builtin_amdgcn_s_setprio(0);                                         \
    if ((KT) + 1 <= lastL) LOADV((KT) + 1)                                 \
  }

  LOADK(t0)
  LOADV(t0)

  f32x16 stA0, stA1, stB0, stB1;
  // prologue: scores(t0) -> A (harmless for empty ranges; tail recomputes)
  QK8(stA0, stA1)
  if (t0 + 1 <= lastL) LOADK(t0 + 1)

  int kt = t0;
  for (; kt + 1 < t1; kt += 2) {
    BODY(stA0, stA1, stB0, stB1, kt)
    BODY(stB0, stB1, stA0, stA1, kt + 1)
  }
  if (kt < t1) BODY(stA0, stA1, stB0, stB1, kt)

  // ---- even qt: diagonal half-tile (kv 0..31 of tile 'last'), st0 only ----
  if (dotail) {
    f32x16 st0;
#pragma unroll
    for (int r = 0; r < 16; ++r) st0[r] = 0.f;
    __builtin_amdgcn_s_setprio(1);
#pragma unroll
    for (int i = 0; i < 4; ++i)
      st0 = __builtin_amdgcn_mfma_f32_32x32x16_bf16(kf0[i].v, qf[i].v, st0, 0, 0, 0);
    __builtin_amdgcn_s_setprio(0);
#pragma unroll
    for (int r = 0; r < 16; ++r) {
      const int kvloc = (r & 3) + 8 * (r >> 2) + 4 * hi;
      st0[r] = (kvloc > c) ? 0.f : exp2f(st0[r]);
    }
#pragma unroll
    for (int r = 0; r < 16; ++r) sacc[r & 3] += st0[r];
    BFU pf0, pf1;
    MAKEPF(pf0, st0[0], st0[1], st0[2], st0[3], st0[4], st0[5], st0[6], st0[7])
    MAKEPF(pf1, st0[8], st0[9], st0[10], st0[11], st0[12], st0[13], st0[14], st0[15])
    __builtin_amdgcn_s_setprio(1);
    acc0 = __builtin_amdgcn_mfma_f32_32x32x16_bf16(vf0[0].v, pf0.v, acc0, 0, 0, 0);
    acc0 = __builtin_amdgcn_mfma_f32_32x32x16_bf16(vf0[1].v, pf1.v, acc0, 0, 0, 0);
    acc1 = __builtin_amdgcn_mfma_f32_32x32x16_bf16(vf1[0].v, pf0.v, acc1, 0, 0, 0);
    acc1 = __builtin_amdgcn_mfma_f32_32x32x16_bf16(vf1[1].v, pf1.v, acc1, 0, 0, 0);
    __builtin_amdgcn_s_setprio(0);
  }
#undef BODY
#undef MAKEPF
#undef QK8
#undef LOADK
#undef LOADV

  const float lpart = (sacc[0] + sacc[1]) + (sacc[2] + sacc[3]);

  if (!heavy) {
    const float lrun = 1.f + xhalf_sum(lpart);
    const float inv = 1.f / lrun;
    float* orow = O + ((size_t)(bh * S_LEN) + qt * 32 + c) * DH;
#pragma unroll
    for (int k = 0; k < 4; ++k) {
      float4 o0, o1;
      o0.x = acc0[4 * k] * inv;     o0.y = acc0[4 * k + 1] * inv;
      o0.z = acc0[4 * k + 2] * inv; o0.w = acc0[4 * k + 3] * inv;
      o1.x = acc1[4 * k] * inv;     o1.y = acc1[4 * k + 1] * inv;
      o1.z = acc1[4 * k + 2] * inv; o1.w = acc1[4 * k + 3] * inv;
      *(float4*)(orow + 8 * k + 4 * hi) = o0;
      *(float4*)(orow + 32 + 8 * k + 4 * hi) = o1;
    }
  } else {
    // ORDER-INDEPENDENT partial index: pid = bh*62 + 2*(63-qt) + part
    const int po = 2 * (63 - qt) + part;
    unsigned char* base = pws + (size_t)(bh * 62 + po) * PSTRIDE + lane * 144;
#pragma unroll
    for (int k = 0; k < 4; ++k) {
      float4 a0, a1;
      a0.x = acc0[4 * k];     a0.y = acc0[4 * k + 1];
      a0.z = acc0[4 * k + 2]; a0.w = acc0[4 * k + 3];
      a1.x = acc1[4 * k];     a1.y = acc1[4 * k + 1];
      a1.z = acc1[4 * k + 2]; a1.w = acc1[4 * k + 3];
      *(float4*)(base + k * 16) = a0;
      *(float4*)(base + 64 + k * 16) = a1;
    }
    *(float*)(base + 128) = lpart;
  }
}

// ---- combine: O = (accA+accB) / (1 + lA + lB) ------------------------------
__global__ __launch_bounds__(64) void combine(const unsigned char* __restrict__ pws,
                                              float* __restrict__ O) {
  const int lane = threadIdx.x;
  const int c = lane & 31;
  const int hi = lane >> 5;
  const int bh = blockIdx.x & 31;
  const int j = blockIdx.x >> 5;       // 0..30 -> qt = 63-j
  const int qt = 63 - j;
  const unsigned char* p0 = pws + (size_t)(bh * 62 + 2 * j) * PSTRIDE + lane * 144;
  const unsigned char* p1 = p0 + PSTRIDE;

  float a0[16], a1[16];
#pragma unroll
  for (int k = 0; k < 4; ++k) {
    float4 x0 = *(const float4*)(p0 + k * 16);
    float4 y0 = *(const float4*)(p1 + k * 16);
    a0[4 * k] = x0.x + y0.x; a0[4 * k + 1] = x0.y + y0.y;
    a0[4 * k + 2] = x0.z + y0.z; a0[4 * k + 3] = x0.w + y0.w;
    float4 x1 = *(const float4*)(p0 + 64 + k * 16);
    float4 y1 = *(const float4*)(p1 + 64 + k * 16);
    a1[4 * k] = x1.x + y1.x; a1[4 * k + 1] = x1.y + y1.y;
    a1[4 * k + 2] = x1.z + y1.z; a1[4 * k + 3] = x1.w + y1.w;
  }
  const float lp = *(const float*)(p0 + 128) + *(const float*)(p1 + 128);
  const float lrun = 1.f + xhalf_sum(lp);
  const float inv = 1.f / lrun;
  float* orow = O + ((size_t)(bh * S_LEN) + qt * 32 + c) * DH;
#pragma unroll
  for (int k = 0; k < 4; ++k) {
    float4 o0, o1;
    o0.x = a0[4 * k] * inv;     o0.y = a0[4 * k + 1] * inv;
    o0.z = a0[4 * k + 2] * inv; o0.w = a0[4 * k + 3] * inv;
    o1.x = a1[4 * k] * inv;     o1.y = a1[4 * k + 1] * inv;
    o1.z = a1[4 * k + 2] * inv; o1.w = a1[4 * k + 3] * inv;
    *(float4*)(orow + 8 * k + 4 * hi) = o0;
    *(float4*)(orow + 32 + 8 * k + 4 * hi) = o1;
  }
}

// ---- mid-tier: R8 kernel (proven 49.7us) for 16MB <= ws < 35MB -------------
__global__ __launch_bounds__(64) void fattn8(const float* __restrict__ Q,
                                             const unsigned char* __restrict__ wsK,
                                             const unsigned char* __restrict__ wsVt,
                                             float* __restrict__ O) {
  const int lane = threadIdx.x;
  const int c = lane & 31;
  const int hi = lane >> 5;

  const int bid = blockIdx.x;
  const int bh = bid & 31;
  const int qt = 63 - (bid >> 5);

  const float* qrow = Q + ((size_t)(bh * S_LEN) + qt * 32 + c) * DH;
  BFU qf[4];
#pragma unroll
  for (int i = 0; i < 4; ++i) {
    const int d0 = i * 16 + hi * 8;
    float4 x = *(const float4*)(qrow + d0);
    float4 y = *(const float4*)(qrow + d0 + 4);
    const float sc = 0.125f * LOG2E;
    qf[i].q.x = pk2(x.x * sc, x.y * sc);
    qf[i].q.y = pk2(x.z * sc, x.w * sc);
    qf[i].q.z = pk2(y.x * sc, y.y * sc);
    qf[i].q.w = pk2(y.z * sc, y.w * sc);
  }

  f32x16 acc0, acc1;
#pragma unroll
  for (int r = 0; r < 16; ++r) { acc0[r] = 0.f; acc1[r] = 0.f; }
  float sacc[16];
#pragma unroll
  for (int r = 0; r < 16; ++r) sacc[r] = 0.f;

  const unsigned char* tbK = wsK + (size_t)bh * 32 * 8192;
  const unsigned char* tbV = wsVt + (size_t)bh * 32 * 8192;
  const int fo = hi * 1024 + c * 16;

  const int NT = (qt + 1) >> 1;
  const int last = qt >> 1;

  BFU kf0[4], kf1[4], vf0[4], vf1[4];
#define LOADK(tile_)                                                       \
  {                                                                        \
    const unsigned char* kb_ = tbK + (size_t)(tile_) * 8192;               \
    _Pragma("unroll")                                                      \
    for (int i = 0; i < 4; ++i) {                                          \
      kf0[i].q = *(const uint4*)(kb_ + i * 2048 + fo);                     \
      kf1[i].q = *(const uint4*)(kb_ + i * 2048 + fo + 512);               \
    }                                                                      \
  }
#define LOADV(tile_)                                                       \
  {                                                                        \
    const unsigned char* vb_ = tbV + (size_t)(tile_) * 8192;               \
    _Pragma("unroll")                                                      \
    for (int i = 0; i < 4; ++i) {                                          \
      vf0[i].q = *(const uint4*)(vb_ + i * 2048 + fo);                     \
      vf1[i].q = *(const uint4*)(vb_ + i * 2048 + fo + 512);               \
    }                                                                      \
  }
#define QK8(D0, D1)                                                        \
  {                                                                        \
    _Pragma("unroll")                                                      \
    for (int r = 0; r < 16; ++r) { (D0)[r] = 0.f; (D1)[r] = 0.f; }         \
    __builtin_amdgcn_s_setprio(1);                                         \
    _Pragma("unroll")                                                      \
    for (int i = 0; i < 4; ++i) {                                          \
      (D0) = __builtin_amdgcn_mfma_f32_32x32x16_bf16(kf0[i].v, qf[i].v, (D0), 0, 0, 0); \
      (D1) = __builtin_amdgcn_mfma_f32_32x32x16_bf16(kf1[i].v, qf[i].v, (D1), 0, 0, 0); \
    }                                                                      \
    __builtin_amdgcn_s_setprio(0);                                         \
  }
#define MAKEPF(dst, x0, x1, x2, x3, y0, y1, y2, y3)                  \
    {                                                                \
      unsigned a01 = cvtpk(x0, x1), a23 = cvtpk(x2, x3);             \
      unsigned b01 = cvtpk(y0, y1), b23 = cvtpk(y2, y3);             \
      asm("v_permlane32_swap_b32 %0, %1" : "+v"(a01), "+v"(b01));    \
      asm("v_permlane32_swap_b32 %0, %1" : "+v"(a23), "+v"(b23));    \
      (dst).q.x = a01; (dst).q.y = a23; (dst).q.z = b01; (dst).q.w = b23; \
    }
#define BODY(S0, S1, N0, N1, KT)                                           \
  {                                                                        \
    if ((KT) + 1 < NT) QK8(N0, N1)                                         \
    if ((KT) + 2 <= last) LOADK((KT) + 2)                                  \
    if ((qt & 1) && (KT) == NT - 1) {                                      \
      _Pragma("unroll")                                                    \
      for (int r = 0; r < 16; ++r) {                                       \
        const int kvloc = (r & 3) + 8 * (r >> 2) + 4 * hi;                 \
        if (kvloc > c) (S1)[r] = -1e9f;                                    \
      }                                                                    \
    }                                                                      \
    _Pragma("unroll")                                                      \
    for (int r = 0; r < 16; ++r) { (S0)[r] = exp2f((S0)[r]); (S1)[r] = exp2f((S1)[r]); } \
    _Pragma("unroll")                                                      \
    for (int r = 0; r < 16; ++r) sacc[r] += (S0)[r] + (S1)[r];             \
    BFU pf[4];                                                             \
    MAKEPF(pf[0], (S0)[0], (S0)[1], (S0)[2], (S0)[3], (S0)[4], (S0)[5], (S0)[6], (S0)[7])  \
    MAKEPF(pf[1], (S0)[8], (S0)[9], (S0)[10], (S0)[11], (S0)[12], (S0)[13], (S0)[14], (S0)[15]) \
    MAKEPF(pf[2], (S1)[0], (S1)[1], (S1)[2], (S1)[3], (S1)[4], (S1)[5], (S1)[6], (S1)[7])  \
    MAKEPF(pf[3], (S1)[8], (S1)[9], (S1)[10], (S1)[11], (S1)[12], (S1)[13], (S1)[14], (S1)[15]) \
    __builtin_amdgcn_s_setprio(1);                                         \
    _Pragma("unroll")                                                      \
    for (int kvt = 0; kvt < 4; ++kvt) {                                    \
      acc0 = __builtin_amdgcn_mfma_f32_32x32x16_bf16(vf0[kvt].v, pf[kvt].v, acc0, 0, 0, 0); \
      acc1 = __builtin_amdgcn_mfma_f32_32x32x16_bf16(vf1[kvt].v, pf[kvt].v, acc1, 0, 0, 0); \
    }                                                                      \
    __builtin_amdgcn_s_setprio(0);                                         \
    if ((KT) + 1 <= last) LOADV((KT) + 1)                                  \
  }

  LOADK(0)
  LOADV(0)

  f32x16 stA0, stA1, stB0, stB1;
  QK8(stA0, stA1)
  if (1 <= last) LOADK(1)

  int kt = 0;
  for (; kt + 1 < NT; kt += 2) {
    BODY(stA0, stA1, stB0, stB1, kt)
    BODY(stB0, stB1, stA0, stA1, kt + 1)
  }
  if (kt < NT) BODY(stA0, stA1, stB0, stB1, kt)

  if (!(qt & 1)) {
    f32x16 st0;
#pragma unroll
    for (int r = 0; r < 16; ++r) st0[r] = 0.f;
    __builtin_amdgcn_s_setprio(1);
#pragma unroll
    for (int i = 0; i < 4; ++i)
      st0 = __builtin_amdgcn_mfma_f32_32x32x16_bf16(kf0[i].v, qf[i].v, st0, 0, 0, 0);
    __builtin_amdgcn_s_setprio(0);
#pragma unroll
    for (int r = 0; r < 16; ++r) {
      const int kvloc = (r & 3) + 8 * (r >> 2) + 4 * hi;
      st0[r] = (kvloc > c) ? 0.f : exp2f(st0[r]);
    }
#pragma unroll
    for (int r = 0; r < 16; ++r) sacc[r] += st0[r];
    BFU pf0, pf1;
    MAKEPF(pf0, st0[0], st0[1], st0[2], st0[3], st0[4], st0[5], st0[6], st0[7])
    MAKEPF(pf1, st0[8], st0[9], st0[10], st0[11], st0[12], st0[13], st0[14], st0[15])
    __builtin_amdgcn_s_setprio(1);
    acc0 = __builtin_amdgcn_mfma_f32_32x32x16_bf16(vf0[0].v, pf0.v, acc0, 0, 0, 0);
    acc0 = __builtin_amdgcn_mfma_f32_32x32x16_bf16(vf0[1].v, pf1.v, acc0, 0, 0, 0);
    acc1 = __builtin_amdgcn_mfma_f32_32x32x16_bf16(vf1[0].v, pf0.v, acc1, 0, 0, 0);
    acc1 = __builtin_amdgcn_mfma_f32_32x32x16_bf16(vf1[1].v, pf1.v, acc1, 0, 0, 0);
    __builtin_amdgcn_s_setprio(0);
  }
#undef BODY
#undef MAKEPF
#undef QK8
#undef LOADK
#undef LOADV

#pragma unroll
  for (int off = 8; off >= 1; off >>= 1)
#pragma unroll
    for (int r = 0; r < 8; ++r)
      if (r < off) sacc[r] += sacc[r + off];
  const float lrun = 1.f + xhalf_sum(sacc[0]);

  const float inv = 1.f / lrun;
  float* orow = O + ((size_t)(bh * S_LEN) + qt * 32 + c) * DH;
#pragma unroll
  for (int k = 0; k < 4; ++k) {
    float4 o0, o1;
    o0.x = acc0[4 * k] * inv;     o0.y = acc0[4 * k + 1] * inv;
    o0.z = acc0[4 * k + 2] * inv; o0.w = acc0[4 * k + 3] * inv;
    o1.x = acc1[4 * k] * inv;     o1.y = acc1[4 * k + 1] * inv;
    o1.z = acc1[4 * k + 2] * inv; o1.w = acc1[4 * k + 3] * inv;
    *(float4*)(orow + 8 * k + 4 * hi) = o0;
    *(float4*)(orow + 32 + 8 * k + 4 * hi) = o1;
  }
}

// ---------------- fallback (R2 staging kernel) if ws too small ----------------
__global__ __launch_bounds__(256) void fattn_fb(const float* __restrict__ Q,
                                                const float* __restrict__ K,
                                                const float* __restrict__ V,
                                                float* __restrict__ O) {
  __shared__ __align__(16) unsigned char lds[24 * 1024];
  unsigned char* kb = lds;
  unsigned char* vb = lds + 8192;
  const int t = threadIdx.x;
  const int lane = t & 63;
  const int w = t >> 6;
  const int g = lane >> 4;
  const int n = lane & 15;
  unsigned char* pb = lds + 16384 + w * 2048;

  const int bid = blockIdx.x;
  const int bh = bid & 31;
  const int qt = bid >> 5;
  const int q0 = qt * 64;

  const float* qg = Q + ((size_t)(bh * S_LEN) + q0 + w * 16 + n) * DH + g * 8;
  BFU qf[2];
#pragma unroll
  for (int cc = 0; cc < 2; ++cc) {
    float4 x = *(const float4*)(qg + 32 * cc);
    float4 y = *(const float4*)(qg + 32 * cc + 4);
    const float sc = 0.125f * LOG2E;
    qf[cc].q.x = pk2(x.x * sc, x.y * sc);
    qf[cc].q.y = pk2(x.z * sc, x.w * sc);
    qf[cc].q.z = pk2(y.x * sc, y.y * sc);
    qf[cc].q.w = pk2(y.z * sc, y.w * sc);
  }

  f32x4 acc[4] = {{0.f,0.f,0.f,0.f},{0.f,0.f,0.f,0.f},{0.f,0.f,0.f,0.f},{0.f,0.f,0.f,0.f}};
  float mrun[4] = {0.f, 0.f, 0.f, 0.f};
  float lrun[4] = {1.f, 1.f, 1.f, 1.f};

  const int sr = t >> 2;
  const int dc = (t & 3) * 16;
  const size_t kvbase = (size_t)(bh * S_LEN) * DH;

  for (int kt = 0; kt <= qt; ++kt) {
    __syncthreads();
    {
      const float* kg = K + kvbase + (size_t)(kt * 64 + sr) * DH + dc;
      float4 k0 = *(const float4*)(kg);
      float4 k1 = *(const float4*)(kg + 4);
      float4 k2 = *(const float4*)(kg + 8);
      float4 k3 = *(const float4*)(kg + 12);
      uint4 h0, h1;
      h0.x = pk2(k0.x, k0.y); h0.y = pk2(k0.z, k0.w);
      h0.z = pk2(k1.x, k1.y); h0.w = pk2(k1.z, k1.w);
      h1.x = pk2(k2.x, k2.y); h1.y = pk2(k2.z, k2.w);
      h1.z = pk2(k3.x, k3.y); h1.w = pk2(k3.z, k3.w);
      const int kbase = sr * 128 + dc * 2;
      const int ksw = (sr & 7) << 4;
      *(uint4*)(kb + ((kbase) ^ ksw)) = h0;
      *(uint4*)(kb + ((kbase + 16) ^ ksw)) = h1;

      const float* vg = V + kvbase + (size_t)(kt * 64 + sr) * DH + dc;
      float4 v0 = *(const float4*)(vg);
      float4 v1 = *(const float4*)(vg + 4);
      float4 v2 = *(const float4*)(vg + 8);
      float4 v3 = *(const float4*)(vg + 12);
      const int r2 = sr * 2;
#define VW(j, val) { const int d_ = dc + (j); \
  *(unsigned short*)(vb + ((d_ * 128 + r2) ^ ((d_ & 7) << 4))) = f2bf(val); }
      VW(0, v0.x) VW(1, v0.y) VW(2, v0.z) VW(3, v0.w)
      VW(4, v1.x) VW(5, v1.y) VW(6, v1.z) VW(7, v1.w)
      VW(8, v2.x) VW(9, v2.y) VW(10, v2.z) VW(11, v2.w)
      VW(12, v3.x) VW(13, v3.y) VW(14, v3.z) VW(15, v3.w)
#undef VW
    }
    __syncthreads();

    f32x4 sv[4] = {{0.f,0.f,0.f,0.f},{0.f,0.f,0.f,0.f},{0.f,0.f,0.f,0.f},{0.f,0.f,0.f,0.f}};
#pragma unroll
    for (int cc = 0; cc < 2; ++cc) {
#pragma unroll
      for (int nt = 0; nt < 4; ++nt) {
        const int kv = nt * 16 + n;
        BFU kf;
        kf.q = *(const uint4*)(kb + ((kv * 128 + g * 16 + cc * 64) ^ ((kv & 7) << 4)));
        sv[nt] = __builtin_amdgcn_mfma_f32_16x16x32_bf16(qf[cc].v, kf.v, sv[nt], 0, 0, 0);
      }
    }

    if (kt == qt) {
#pragma unroll
      for (int nt = 0; nt < 4; ++nt)
#pragma unroll
        for (int r = 0; r < 4; ++r)
          if (nt * 16 + n > w * 16 + g * 4 + r) sv[nt][r] = -1e9f;
    }

#pragma unroll
    for (int r = 0; r < 4; ++r) {
      float s0 = sv[0][r], s1 = sv[1][r], s2 = sv[2][r], s3 = sv[3][r];
      float mx = fmaxf(fmaxf(s0, s1), fmaxf(s2, s3));
#pragma unroll
      for (int off = 1; off < 16; off <<= 1) mx = fmaxf(mx, __shfl_xor(mx, off));
      const float mnew = fmaxf(mrun[r], mx);
      const float p0 = exp2f(s0 - mnew);
      const float p1 = exp2f(s1 - mnew);
      const float p2 = exp2f(s2 - mnew);
      const float p3 = exp2f(s3 - mnew);
      float sum = (p0 + p1) + (p2 + p3);
#pragma unroll
      for (int off = 1; off < 16; off <<= 1) sum += __shfl_xor(sum, off);
      const float scale = exp2f(mrun[r] - mnew);
      lrun[r] = lrun[r] * scale + sum;
      mrun[r] = mnew;
      acc[0][r] *= scale; acc[1][r] *= scale; acc[2][r] *= scale; acc[3][r] *= scale;
      const int row = g * 4 + r;
      const int rb = row * 128;
      const int sw = (row & 7) << 4;
      *(unsigned short*)(pb + ((rb + (0 * 16 + n) * 2) ^ sw)) = f2bf(p0);
      *(unsigned short*)(pb + ((rb + (1 * 16 + n) * 2) ^ sw)) = f2bf(p1);
      *(unsigned short*)(pb + ((rb + (2 * 16 + n) * 2) ^ sw)) = f2bf(p2);
      *(unsigned short*)(pb + ((rb + (3 * 16 + n) * 2) ^ sw)) = f2bf(p3);
    }

#pragma unroll
    for (int cc = 0; cc < 2; ++cc) {
      BFU pfr;
      pfr.q = *(const uint4*)(pb + ((n * 128 + g * 16 + cc * 64) ^ ((n & 7) << 4)));
#pragma unroll
      for (int nt = 0; nt < 4; ++nt) {
        const int d_ = nt * 16 + n;
        BFU vf;
        vf.q = *(const uint4*)(vb + ((d_ * 128 + g * 16 + cc * 64) ^ ((d_ & 7) << 4)));
        acc[nt] = __builtin_amdgcn_mfma_f32_16x16x32_bf16(pfr.v, vf.v, acc[nt], 0, 0, 0);
      }
    }
  }

#pragma unroll
  for (int r = 0; r < 4; ++r) {
    const float inv = 1.f / lrun[r];
    float* op = O + ((size_t)(bh * S_LEN) + q0 + w * 16 + g * 4 + r) * DH + n;
    op[0]  = acc[0][r] * inv;
    op[16] = acc[1][r] * inv;
    op[32] = acc[2][r] * inv;
    op[48] = acc[3][r] * inv;
  }
}

extern "C" void kernel_launch(void* const* d_in, const int* in_sizes, int n_in,
                              void* d_out, int out_size, void* d_ws, size_t ws_size,
                              hipStream_t stream) {
  const float* Q = (const float*)d_in[0];
  const float* K = (const float*)d_in[1];
  const float* V = (const float*)d_in[2];
  float* O = (float*)d_out;
  const size_t need_pack = (size_t)1024 * 8192 * 2;            // 16 MB tiles
  const size_t need_split = need_pack + (size_t)1984 * PSTRIDE; // + 18.3 MB partials
  if (ws_size >= need_split) {
    unsigned char* wsK = (unsigned char*)d_ws;
    unsigned char* wsVt = wsK + (size_t)1024 * 8192;
    unsigned char* pws = wsVt + (size_t)1024 * 8192;
    prepack<<<dim3(1024), dim3(256), 0, stream>>>(K, V, wsK, wsVt);
    fattn12<<<dim3(3040), dim3(64), 0, stream>>>(Q, wsK, wsVt, pws, O);
    combine<<<dim3(992), dim3(64), 0, stream>>>(pws, O);
  } else if (ws_size >= need_pack) {
    unsigned char* wsK = (unsigned char*)d_ws;
    unsigned char* wsVt = wsK + (size_t)1024 * 8192;
    prepack<<<dim3(1024), dim3(256), 0, stream>>>(K, V, wsK, wsVt);
    fattn8<<<dim3(2048), dim3(64), 0, stream>>>(Q, wsK, wsVt, O);
  } else {
    fattn_fb<<<dim3(1024), dim3(256), 0, stream>>>(Q, K, V, O);
  }
}

// Round 13
// 41.442 us; speedup vs baseline: 5.2522x; 1.5184x over previous
//
#include <hip/hip_runtime.h>

typedef __attribute__((ext_vector_type(8))) short bf16x8;
typedef __attribute__((ext_vector_type(4))) float f32x4;
typedef __attribute__((ext_vector_type(16))) float f32x16;

union BFU { uint4 q; bf16x8 v; };

__device__ __forceinline__ unsigned short f2bf(float f) {
  unsigned u = __float_as_uint(f);
  u += 0x7fff + ((u >> 16) & 1);
  return (unsigned short)(u >> 16);
}
__device__ __forceinline__ unsigned pk2(float a, float b) {
  return (unsigned)f2bf(a) | ((unsigned)f2bf(b) << 16);
}
__device__ __forceinline__ unsigned cvtpk(float lo, float hi) {
  unsigned d;
  asm("v_cvt_pk_bf16_f32 %0, %1, %2" : "=v"(d) : "v"(lo), "v"(hi));
  return d;
}
__device__ __forceinline__ float xhalf_sum(float x) {
  return x + __shfl_xor(x, 32);
}
// Raw v_exp_f32: OCML exp2f carries a denormal-range fixup (~5 VALU/call);
// our domain (|s2| < 60, or -1e9 -> 0) needs none of it. 32 calls/tile on
// the binding VALU pipe -> this is the R13 single-variable change.
#if __has_builtin(__builtin_amdgcn_exp2f)
__device__ __forceinline__ float fexp2(float x) { return __builtin_amdgcn_exp2f(x); }
#else
__device__ __forceinline__ float fexp2(float x) {
  float r;
  asm("v_exp_f32 %0, %1\n\ts_nop 1" : "=v"(r) : "v"(x));
  return r;
}
#endif

#define S_LEN 2048
#define DH 64
#define LOG2E 1.4426950408889634f

// ---- pre-pass: fragment-major bf16 tiles (proven R7/R8) --------------------
__global__ __launch_bounds__(256) void prepack(const float* __restrict__ K,
                                               const float* __restrict__ V,
                                               unsigned char* __restrict__ wsK,
                                               unsigned char* __restrict__ wsVt) {
  const int t = threadIdx.x;
  const int bid = blockIdx.x;              // bh*32 + kt
  const size_t gbase = (size_t)bid * 4096;
  const int row = t & 63;
  const int j = t >> 6;                    // 0..3
  unsigned char* obK = wsK + (size_t)bid * 8192;
  unsigned char* obV = wsVt + (size_t)bid * 8192;
#pragma unroll
  for (int gg = 0; gg < 2; ++gg) {
    const int g = j + gg * 4;              // 0..7
    {
      const float* kg = K + gbase + (size_t)row * DH + g * 8;
      float4 x = *(const float4*)kg;
      float4 y = *(const float4*)(kg + 4);
      uint4 h;
      h.x = pk2(x.x, x.y); h.y = pk2(x.z, x.w);
      h.z = pk2(y.x, y.y); h.w = pk2(y.z, y.w);
      *(uint4*)(obK + g * 1024 + row * 16) = h;
    }
    {
      const float* vg = V + gbase + row;
      float v0 = vg[(size_t)(g * 8 + 0) * DH], v1 = vg[(size_t)(g * 8 + 1) * DH];
      float v2 = vg[(size_t)(g * 8 + 2) * DH], v3 = vg[(size_t)(g * 8 + 3) * DH];
      float v4 = vg[(size_t)(g * 8 + 4) * DH], v5 = vg[(size_t)(g * 8 + 5) * DH];
      float v6 = vg[(size_t)(g * 8 + 6) * DH], v7 = vg[(size_t)(g * 8 + 7) * DH];
      uint4 h;
      h.x = pk2(v0, v1); h.y = pk2(v2, v3);
      h.z = pk2(v4, v5); h.w = pk2(v6, v7);
      *(uint4*)(obV + g * 1024 + row * 16) = h;
    }
  }
}

// ---- main (R8 structure, proven 49.7us total): 1-wave blocks, fixed-m ghost
// softmax, 2-stage software pipeline, LPT. Only change vs R8: fexp2. ---------
__global__ __launch_bounds__(64) void fattn13(const float* __restrict__ Q,
                                              const unsigned char* __restrict__ wsK,
                                              const unsigned char* __restrict__ wsVt,
                                              float* __restrict__ O) {
  const int lane = threadIdx.x;
  const int c = lane & 31;
  const int hi = lane >> 5;

  const int bid = blockIdx.x;
  const int bh = bid & 31;            // 4 bh per XCD -> K/Vt L2-resident
  const int qt = 63 - (bid >> 5);     // LPT

  const float* qrow = Q + ((size_t)(bh * S_LEN) + qt * 32 + c) * DH;
  BFU qf[4];
#pragma unroll
  for (int i = 0; i < 4; ++i) {
    const int d0 = i * 16 + hi * 8;
    float4 x = *(const float4*)(qrow + d0);
    float4 y = *(const float4*)(qrow + d0 + 4);
    const float sc = 0.125f * LOG2E;
    qf[i].q.x = pk2(x.x * sc, x.y * sc);
    qf[i].q.y = pk2(x.z * sc, x.w * sc);
    qf[i].q.z = pk2(y.x * sc, y.y * sc);
    qf[i].q.w = pk2(y.z * sc, y.w * sc);
  }

  f32x16 acc0, acc1;
#pragma unroll
  for (int r = 0; r < 16; ++r) { acc0[r] = 0.f; acc1[r] = 0.f; }
  // fixed-m ghost softmax: m = 0; denominator deferred; ghost adds 1.
  float sacc[16];
#pragma unroll
  for (int r = 0; r < 16; ++r) sacc[r] = 0.f;

  const unsigned char* tbK = wsK + (size_t)bh * 32 * 8192;
  const unsigned char* tbV = wsVt + (size_t)bh * 32 * 8192;
  const int fo = hi * 1024 + c * 16;

  const int NT = (qt + 1) >> 1;
  const int last = qt >> 1;

  BFU kf0[4], kf1[4], vf0[4], vf1[4];
#define LOADK(tile_)                                                       \
  {                                                                        \
    const unsigned char* kb_ = tbK + (size_t)(tile_) * 8192;               \
    _Pragma("unroll")                                                      \
    for (int i = 0; i < 4; ++i) {                                          \
      kf0[i].q = *(const uint4*)(kb_ + i * 2048 + fo);                     \
      kf1[i].q = *(const uint4*)(kb_ + i * 2048 + fo + 512);               \
    }                                                                      \
  }
#define LOADV(tile_)                                                       \
  {                                                                        \
    const unsigned char* vb_ = tbV + (size_t)(tile_) * 8192;               \
    _Pragma("unroll")                                                      \
    for (int i = 0; i < 4; ++i) {                                          \
      vf0[i].q = *(const uint4*)(vb_ + i * 2048 + fo);                     \
      vf1[i].q = *(const uint4*)(vb_ + i * 2048 + fo + 512);               \
    }                                                                      \
  }
#define QK8(D0, D1)                                                        \
  {                                                                        \
    _Pragma("unroll")                                                      \
    for (int r = 0; r < 16; ++r) { (D0)[r] = 0.f; (D1)[r] = 0.f; }         \
    __builtin_amdgcn_s_setprio(1);                                         \
    _Pragma("unroll")                                                      \
    for (int i = 0; i < 4; ++i) {                                          \
      (D0) = __builtin_amdgcn_mfma_f32_32x32x16_bf16(kf0[i].v, qf[i].v, (D0), 0, 0, 0); \
      (D1) = __builtin_amdgcn_mfma_f32_32x32x16_bf16(kf1[i].v, qf[i].v, (D1), 0, 0, 0); \
    }                                                                      \
    __builtin_amdgcn_s_setprio(0);                                         \
  }
#define MAKEPF(dst, x0, x1, x2, x3, y0, y1, y2, y3)                  \
    {                                                                \
      unsigned a01 = cvtpk(x0, x1), a23 = cvtpk(x2, x3);             \
      unsigned b01 = cvtpk(y0, y1), b23 = cvtpk(y2, y3);             \
      asm("v_permlane32_swap_b32 %0, %1" : "+v"(a01), "+v"(b01));    \
      asm("v_permlane32_swap_b32 %0, %1" : "+v"(a23), "+v"(b23));    \
      (dst).q.x = a01; (dst).q.y = a23; (dst).q.z = b01; (dst).q.w = b23; \
    }
#define BODY(S0, S1, N0, N1, KT)                                           \
  {                                                                        \
    if ((KT) + 1 < NT) QK8(N0, N1)          /* overlaps exp/PV below */    \
    if ((KT) + 2 <= last) LOADK((KT) + 2)                                  \
    if ((qt & 1) && (KT) == NT - 1) {                                      \
      _Pragma("unroll")                                                    \
      for (int r = 0; r < 16; ++r) {                                       \
        const int kvloc = (r & 3) + 8 * (r >> 2) + 4 * hi;                 \
        if (kvloc > c) (S1)[r] = -1e9f;                                    \
      }                                                                    \
    }                                                                      \
    _Pragma("unroll")                                                      \
    for (int r = 0; r < 16; ++r) { (S0)[r] = fexp2((S0)[r]); (S1)[r] = fexp2((S1)[r]); } \
    _Pragma("unroll")                                                      \
    for (int r = 0; r < 16; ++r) sacc[r] += (S0)[r] + (S1)[r];             \
    BFU pf[4];                                                             \
    MAKEPF(pf[0], (S0)[0], (S0)[1], (S0)[2], (S0)[3], (S0)[4], (S0)[5], (S0)[6], (S0)[7])  \
    MAKEPF(pf[1], (S0)[8], (S0)[9], (S0)[10], (S0)[11], (S0)[12], (S0)[13], (S0)[14], (S0)[15]) \
    MAKEPF(pf[2], (S1)[0], (S1)[1], (S1)[2], (S1)[3], (S1)[4], (S1)[5], (S1)[6], (S1)[7])  \
    MAKEPF(pf[3], (S1)[8], (S1)[9], (S1)[10], (S1)[11], (S1)[12], (S1)[13], (S1)[14], (S1)[15]) \
    __builtin_amdgcn_s_setprio(1);                                         \
    _Pragma("unroll")                                                      \
    for (int kvt = 0; kvt < 4; ++kvt) {                                    \
      acc0 = __builtin_amdgcn_mfma_f32_32x32x16_bf16(vf0[kvt].v, pf[kvt].v, acc0, 0, 0, 0); \
      acc1 = __builtin_amdgcn_mfma_f32_32x32x16_bf16(vf1[kvt].v, pf[kvt].v, acc1, 0, 0, 0); \
    }                                                                      \
    __builtin_amdgcn_s_setprio(0);                                         \
    if ((KT) + 1 <= last) LOADV((KT) + 1)                                  \
  }

  LOADK(0)
  LOADV(0)

  f32x16 stA0, stA1, stB0, stB1;
  QK8(stA0, stA1)
  if (1 <= last) LOADK(1)

  int kt = 0;
  for (; kt + 1 < NT; kt += 2) {
    BODY(stA0, stA1, stB0, stB1, kt)
    BODY(stB0, stB1, stA0, stA1, kt + 1)
  }
  if (kt < NT) BODY(stA0, stA1, stB0, stB1, kt)

  // ---- even qt: diagonal half-tile (kv 0..31 of tile 'last'), st0 only ----
  if (!(qt & 1)) {
    f32x16 st0;
#pragma unroll
    for (int r = 0; r < 16; ++r) st0[r] = 0.f;
    __builtin_amdgcn_s_setprio(1);
#pragma unroll
    for (int i = 0; i < 4; ++i)
      st0 = __builtin_amdgcn_mfma_f32_32x32x16_bf16(kf0[i].v, qf[i].v, st0, 0, 0, 0);
    __builtin_amdgcn_s_setprio(0);
#pragma unroll
    for (int r = 0; r < 16; ++r) {
      const int kvloc = (r & 3) + 8 * (r >> 2) + 4 * hi;
      st0[r] = (kvloc > c) ? 0.f : fexp2(st0[r]);
    }
#pragma unroll
    for (int r = 0; r < 16; ++r) sacc[r] += st0[r];
    BFU pf0, pf1;
    MAKEPF(pf0, st0[0], st0[1], st0[2], st0[3], st0[4], st0[5], st0[6], st0[7])
    MAKEPF(pf1, st0[8], st0[9], st0[10], st0[11], st0[12], st0[13], st0[14], st0[15])
    __builtin_amdgcn_s_setprio(1);
    acc0 = __builtin_amdgcn_mfma_f32_32x32x16_bf16(vf0[0].v, pf0.v, acc0, 0, 0, 0);
    acc0 = __builtin_amdgcn_mfma_f32_32x32x16_bf16(vf0[1].v, pf1.v, acc0, 0, 0, 0);
    acc1 = __builtin_amdgcn_mfma_f32_32x32x16_bf16(vf1[0].v, pf0.v, acc1, 0, 0, 0);
    acc1 = __builtin_amdgcn_mfma_f32_32x32x16_bf16(vf1[1].v, pf1.v, acc1, 0, 0, 0);
    __builtin_amdgcn_s_setprio(0);
  }
#undef BODY
#undef MAKEPF
#undef QK8
#undef LOADK
#undef LOADV

  // ---- denominator: one tree + one cross-half shfl; ghost adds 1.0 ----
#pragma unroll
  for (int off = 8; off >= 1; off >>= 1)
#pragma unroll
    for (int r = 0; r < 8; ++r)
      if (r < off) sacc[r] += sacc[r + off];
  const float lrun = 1.f + xhalf_sum(sacc[0]);

  const float inv = 1.f / lrun;
  float* orow = O + ((size_t)(bh * S_LEN) + qt * 32 + c) * DH;
#pragma unroll
  for (int k = 0; k < 4; ++k) {
    float4 o0, o1;
    o0.x = acc0[4 * k] * inv;     o0.y = acc0[4 * k + 1] * inv;
    o0.z = acc0[4 * k + 2] * inv; o0.w = acc0[4 * k + 3] * inv;
    o1.x = acc1[4 * k] * inv;     o1.y = acc1[4 * k + 1] * inv;
    o1.z = acc1[4 * k + 2] * inv; o1.w = acc1[4 * k + 3] * inv;
    *(float4*)(orow + 8 * k + 4 * hi) = o0;
    *(float4*)(orow + 32 + 8 * k + 4 * hi) = o1;
  }
}

// ---------------- fallback (R2 staging kernel) if ws too small ----------------
__global__ __launch_bounds__(256) void fattn_fb(const float* __restrict__ Q,
                                                const float* __restrict__ K,
                                                const float* __restrict__ V,
                                                float* __restrict__ O) {
  __shared__ __align__(16) unsigned char lds[24 * 1024];
  unsigned char* kb = lds;
  unsigned char* vb = lds + 8192;
  const int t = threadIdx.x;
  const int lane = t & 63;
  const int w = t >> 6;
  const int g = lane >> 4;
  const int n = lane & 15;
  unsigned char* pb = lds + 16384 + w * 2048;

  const int bid = blockIdx.x;
  const int bh = bid & 31;
  const int qt = bid >> 5;
  const int q0 = qt * 64;

  const float* qg = Q + ((size_t)(bh * S_LEN) + q0 + w * 16 + n) * DH + g * 8;
  BFU qf[2];
#pragma unroll
  for (int cc = 0; cc < 2; ++cc) {
    float4 x = *(const float4*)(qg + 32 * cc);
    float4 y = *(const float4*)(qg + 32 * cc + 4);
    const float sc = 0.125f * LOG2E;
    qf[cc].q.x = pk2(x.x * sc, x.y * sc);
    qf[cc].q.y = pk2(x.z * sc, x.w * sc);
    qf[cc].q.z = pk2(y.x * sc, y.y * sc);
    qf[cc].q.w = pk2(y.z * sc, y.w * sc);
  }

  f32x4 acc[4] = {{0.f,0.f,0.f,0.f},{0.f,0.f,0.f,0.f},{0.f,0.f,0.f,0.f},{0.f,0.f,0.f,0.f}};
  float mrun[4] = {0.f, 0.f, 0.f, 0.f};
  float lrun[4] = {1.f, 1.f, 1.f, 1.f};

  const int sr = t >> 2;
  const int dc = (t & 3) * 16;
  const size_t kvbase = (size_t)(bh * S_LEN) * DH;

  for (int kt = 0; kt <= qt; ++kt) {
    __syncthreads();
    {
      const float* kg = K + kvbase + (size_t)(kt * 64 + sr) * DH + dc;
      float4 k0 = *(const float4*)(kg);
      float4 k1 = *(const float4*)(kg + 4);
      float4 k2 = *(const float4*)(kg + 8);
      float4 k3 = *(const float4*)(kg + 12);
      uint4 h0, h1;
      h0.x = pk2(k0.x, k0.y); h0.y = pk2(k0.z, k0.w);
      h0.z = pk2(k1.x, k1.y); h0.w = pk2(k1.z, k1.w);
      h1.x = pk2(k2.x, k2.y); h1.y = pk2(k2.z, k2.w);
      h1.z = pk2(k3.x, k3.y); h1.w = pk2(k3.z, k3.w);
      const int kbase = sr * 128 + dc * 2;
      const int ksw = (sr & 7) << 4;
      *(uint4*)(kb + ((kbase) ^ ksw)) = h0;
      *(uint4*)(kb + ((kbase + 16) ^ ksw)) = h1;

      const float* vg = V + kvbase + (size_t)(kt * 64 + sr) * DH + dc;
      float4 v0 = *(const float4*)(vg);
      float4 v1 = *(const float4*)(vg + 4);
      float4 v2 = *(const float4*)(vg + 8);
      float4 v3 = *(const float4*)(vg + 12);
      const int r2 = sr * 2;
#define VW(j, val) { const int d_ = dc + (j); \
  *(unsigned short*)(vb + ((d_ * 128 + r2) ^ ((d_ & 7) << 4))) = f2bf(val); }
      VW(0, v0.x) VW(1, v0.y) VW(2, v0.z) VW(3, v0.w)
      VW(4, v1.x) VW(5, v1.y) VW(6, v1.z) VW(7, v1.w)
      VW(8, v2.x) VW(9, v2.y) VW(10, v2.z) VW(11, v2.w)
      VW(12, v3.x) VW(13, v3.y) VW(14, v3.z) VW(15, v3.w)
#undef VW
    }
    __syncthreads();

    f32x4 sv[4] = {{0.f,0.f,0.f,0.f},{0.f,0.f,0.f,0.f},{0.f,0.f,0.f,0.f},{0.f,0.f,0.f,0.f}};
#pragma unroll
    for (int cc = 0; cc < 2; ++cc) {
#pragma unroll
      for (int nt = 0; nt < 4; ++nt) {
        const int kv = nt * 16 + n;
        BFU kf;
        kf.q = *(const uint4*)(kb + ((kv * 128 + g * 16 + cc * 64) ^ ((kv & 7) << 4)));
        sv[nt] = __builtin_amdgcn_mfma_f32_16x16x32_bf16(qf[cc].v, kf.v, sv[nt], 0, 0, 0);
      }
    }

    if (kt == qt) {
#pragma unroll
      for (int nt = 0; nt < 4; ++nt)
#pragma unroll
        for (int r = 0; r < 4; ++r)
          if (nt * 16 + n > w * 16 + g * 4 + r) sv[nt][r] = -1e9f;
    }

#pragma unroll
    for (int r = 0; r < 4; ++r) {
      float s0 = sv[0][r], s1 = sv[1][r], s2 = sv[2][r], s3 = sv[3][r];
      float mx = fmaxf(fmaxf(s0, s1), fmaxf(s2, s3));
#pragma unroll
      for (int off = 1; off < 16; off <<= 1) mx = fmaxf(mx, __shfl_xor(mx, off));
      const float mnew = fmaxf(mrun[r], mx);
      const float p0 = fexp2(s0 - mnew);
      const float p1 = fexp2(s1 - mnew);
      const float p2 = fexp2(s2 - mnew);
      const float p3 = fexp2(s3 - mnew);
      float sum = (p0 + p1) + (p2 + p3);
#pragma unroll
      for (int off = 1; off < 16; off <<= 1) sum += __shfl_xor(sum, off);
      const float scale = fexp2(mrun[r] - mnew);
      lrun[r] = lrun[r] * scale + sum;
      mrun[r] = mnew;
      acc[0][r] *= scale; acc[1][r] *= scale; acc[2][r] *= scale; acc[3][r] *= scale;
      const int row = g * 4 + r;
      const int rb = row * 128;
      const int sw = (row & 7) << 4;
      *(unsigned short*)(pb + ((rb + (0 * 16 + n) * 2) ^ sw)) = f2bf(p0);
      *(unsigned short*)(pb + ((rb + (1 * 16 + n) * 2) ^ sw)) = f2bf(p1);
      *(unsigned short*)(pb + ((rb + (2 * 16 + n) * 2) ^ sw)) = f2bf(p2);
      *(unsigned short*)(pb + ((rb + (3 * 16 + n) * 2) ^ sw)) = f2bf(p3);
    }

#pragma unroll
    for (int cc = 0; cc < 2; ++cc) {
      BFU pfr;
      pfr.q = *(const uint4*)(pb + ((n * 128 + g * 16 + cc * 64) ^ ((n & 7) << 4)));
#pragma unroll
      for (int nt = 0; nt < 4; ++nt) {
        const int d_ = nt * 16 + n;
        BFU vf;
        vf.q = *(const uint4*)(vb + ((d_ * 128 + g * 16 + cc * 64) ^ ((d_ & 7) << 4)));
        acc[nt] = __builtin_amdgcn_mfma_f32_16x16x32_bf16(pfr.v, vf.v, acc[nt], 0, 0, 0);
      }
    }
  }

#pragma unroll
  for (int r = 0; r < 4; ++r) {
    const float inv = 1.f / lrun[r];
    float* op = O + ((size_t)(bh * S_LEN) + q0 + w * 16 + g * 4 + r) * DH + n;
    op[0]  = acc[0][r] * inv;
    op[16] = acc[1][r] * inv;
    op[32] = acc[2][r] * inv;
    op[48] = acc[3][r] * inv;
  }
}

extern "C" void kernel_launch(void* const* d_in, const int* in_sizes, int n_in,
                              void* d_out, int out_size, void* d_ws, size_t ws_size,
                              hipStream_t stream) {
  const float* Q = (const float*)d_in[0];
  const float* K = (const float*)d_in[1];
  const float* V = (const float*)d_in[2];
  float* O = (float*)d_out;
  const size_t need_pack = (size_t)1024 * 8192 * 2;  // 16 MB prepacked tiles
  if (ws_size >= need_pack) {
    unsigned char* wsK = (unsigned char*)d_ws;
    unsigned char* wsVt = wsK + (size_t)1024 * 8192;
    prepack<<<dim3(1024), dim3(256), 0, stream>>>(K, V, wsK, wsVt);
    fattn13<<<dim3(2048), dim3(64), 0, stream>>>(Q, wsK, wsVt, O);
  } else {
    fattn_fb<<<dim3(1024), dim3(256), 0, stream>>>(Q, K, V, O);
  }
}